// Round 1
// baseline (2251.382 us; speedup 1.0000x reference)
//
#include <hip/hip_runtime.h>
#include <math.h>

// Problem constants (match reference)
#define BB    64          // graphs
#define NN    512         // nodes per graph
#define DD    32          // feature dim
#define EE    16384       // edges per graph
#define NTOT  32768       // B*N total nodes
#define TOTE  1048576     // B*E total edges
#define HA    64
#define HC    64
#define BN_EPS 1e-5f

#define AGG_SPLIT 8
#define AGG_CHUNK (EE / AGG_SPLIT)   // 2048 edges per block

// ---------------------------------------------------------------- zero stats
__global__ void k_zero(float* __restrict__ stats) {
    if (threadIdx.x < 384) stats[threadIdx.x] = 0.f;
}

// ---------------------------------------------------------------- copy (float4)
__global__ __launch_bounds__(256) void k_copy(const float4* __restrict__ src,
                                              float4* __restrict__ dst) {
    int i = blockIdx.x * 256 + threadIdx.x;
    dst[i] = src[i];
}

// ---------------------------------------------------------------- aggregation
// y must be pre-initialized to the layer input (self term). Each block owns
// (graph g, edge-chunk) and accumulates neighbor sums for BOTH edge directions
// into a per-graph LDS partial, then atomically flushes to y (coalesced).
__global__ __launch_bounds__(256) void k_agg(const float* __restrict__ feats,
                                             const int* __restrict__ esrc,
                                             const int* __restrict__ edst,
                                             float* __restrict__ y) {
    __shared__ float acc[NN * DD];   // 64 KB
    int g     = blockIdx.x / AGG_SPLIT;
    int chunk = blockIdx.x % AGG_SPLIT;
    for (int i = threadIdx.x; i < NN * DD; i += 256) acc[i] = 0.f;
    __syncthreads();

    int d    = threadIdx.x & 31;   // feature lane: LDS bank = d -> conflict-free
    int slot = threadIdx.x >> 5;   // 8 edge-dir slots
    int ebase = g * EE + chunk * AGG_CHUNK;
    int nbase = g * NN;
    #pragma unroll 4
    for (int j = slot; j < 2 * AGG_CHUNK; j += 8) {
        int eidx = ebase + (j >> 1);
        int s = esrc[eidx];
        int t = edst[eidx];
        int u = (j & 1) ? t : s;   // value source
        int v = (j & 1) ? s : t;   // accumulate target
        float val = feats[u * DD + d];
        atomicAdd(&acc[(v - nbase) * DD + d], val);
    }
    __syncthreads();
    int obase = g * NN * DD;
    for (int i = threadIdx.x; i < NN * DD; i += 256)
        atomicAdd(&y[obase + i], acc[i]);
}

// ---------------------------------------------------------------- h = X@W + b, col stats
__global__ __launch_bounds__(256) void k_mm_stats(const float* __restrict__ X,
                                                  const float* __restrict__ W,
                                                  const float* __restrict__ bias,
                                                  float* __restrict__ Hout,
                                                  float* __restrict__ stats) {
    __shared__ float Wsh[DD * DD];
    __shared__ float ssum[DD], ssq[DD];
    int tid = threadIdx.x;
    for (int i = tid; i < DD * DD; i += 256) Wsh[i] = W[i];
    if (tid < DD) { ssum[tid] = 0.f; ssq[tid] = 0.f; }
    __syncthreads();

    int c = tid & 31, r = tid >> 5;
    int row = blockIdx.x * 8 + r;
    const float4* xr = (const float4*)(X + row * DD);
    float accv = bias[c];
    #pragma unroll
    for (int k4 = 0; k4 < DD / 4; ++k4) {
        float4 xv = xr[k4];
        accv = fmaf(xv.x, Wsh[(k4 * 4 + 0) * DD + c], accv);
        accv = fmaf(xv.y, Wsh[(k4 * 4 + 1) * DD + c], accv);
        accv = fmaf(xv.z, Wsh[(k4 * 4 + 2) * DD + c], accv);
        accv = fmaf(xv.w, Wsh[(k4 * 4 + 3) * DD + c], accv);
    }
    Hout[row * DD + c] = accv;
    atomicAdd(&ssum[c], accv);
    atomicAdd(&ssq[c], accv * accv);
    __syncthreads();
    if (tid < DD) {
        atomicAdd(&stats[tid], ssum[tid]);
        atomicAdd(&stats[DD + tid], ssq[tid]);
    }
}

// ---------------------------------------------------------------- relu(bn(Hin)) @ W + b
__global__ __launch_bounds__(256) void k_bnmm(const float* __restrict__ Hin,
                                              const float* __restrict__ instats,
                                              const float* __restrict__ gamma,
                                              const float* __restrict__ beta,
                                              const float* __restrict__ W,
                                              const float* __restrict__ bias,
                                              float* __restrict__ Hout,
                                              float* __restrict__ ycopy,
                                              float* __restrict__ outstats) {
    __shared__ float Wsh[DD * DD];
    __shared__ float As[DD], Cs[DD];
    __shared__ float ssum[DD], ssq[DD];
    int tid = threadIdx.x;
    for (int i = tid; i < DD * DD; i += 256) Wsh[i] = W[i];
    if (tid < DD) {
        float s  = instats[tid];
        float q  = instats[DD + tid];
        float mu = s * (1.f / NTOT);
        float var = q * (1.f / NTOT) - mu * mu;
        float a  = gamma[tid] * rsqrtf(var + BN_EPS);
        As[tid]  = a;
        Cs[tid]  = beta[tid] - mu * a;
        ssum[tid] = 0.f; ssq[tid] = 0.f;
    }
    __syncthreads();

    int c = tid & 31, r = tid >> 5;
    int row = blockIdx.x * 8 + r;
    const float4* xr = (const float4*)(Hin + row * DD);
    float accv = bias[c];
    #pragma unroll
    for (int k4 = 0; k4 < DD / 4; ++k4) {
        float4 xv = xr[k4];
        float xn;
        xn = fmaxf(fmaf(xv.x, As[k4 * 4 + 0], Cs[k4 * 4 + 0]), 0.f);
        accv = fmaf(xn, Wsh[(k4 * 4 + 0) * DD + c], accv);
        xn = fmaxf(fmaf(xv.y, As[k4 * 4 + 1], Cs[k4 * 4 + 1]), 0.f);
        accv = fmaf(xn, Wsh[(k4 * 4 + 1) * DD + c], accv);
        xn = fmaxf(fmaf(xv.z, As[k4 * 4 + 2], Cs[k4 * 4 + 2]), 0.f);
        accv = fmaf(xn, Wsh[(k4 * 4 + 2) * DD + c], accv);
        xn = fmaxf(fmaf(xv.w, As[k4 * 4 + 3], Cs[k4 * 4 + 3]), 0.f);
        accv = fmaf(xn, Wsh[(k4 * 4 + 3) * DD + c], accv);
    }
    Hout[row * DD + c] = accv;
    if (ycopy) ycopy[row * DD + c] = accv;
    if (outstats) {
        atomicAdd(&ssum[c], accv);
        atomicAdd(&ssq[c], accv * accv);
        __syncthreads();
        if (tid < DD) {
            atomicAdd(&outstats[tid], ssum[tid]);
            atomicAdd(&outstats[DD + tid], ssq[tid]);
        }
    }
}

// ---------------------------------------------------------------- pool + critic
__global__ __launch_bounds__(256) void k_pool_critic(const float* __restrict__ feats,
                                                     float* __restrict__ gemb,
                                                     const float* __restrict__ W1,
                                                     const float* __restrict__ b1,
                                                     const float* __restrict__ W2,
                                                     const float* __restrict__ b2,
                                                     const float* __restrict__ W3,
                                                     const float* __restrict__ b3,
                                                     float* __restrict__ value) {
    int g = blockIdx.x;
    __shared__ float red[8][DD];
    __shared__ float ge[DD];
    __shared__ float h1[HC];
    __shared__ float h2[HC];
    int tid = threadIdx.x;
    int d = tid & 31, grp = tid >> 5;
    float s = 0.f;
    const float* fg = feats + g * NN * DD;
    for (int n = grp; n < NN; n += 8) s += fg[n * DD + d];
    red[grp][d] = s;
    __syncthreads();
    if (tid < DD) {
        float t = 0.f;
        #pragma unroll
        for (int i = 0; i < 8; ++i) t += red[i][tid];
        t *= (1.f / NN);
        ge[tid] = t;
        gemb[g * DD + tid] = t;
    }
    __syncthreads();
    if (tid < HC) {
        float a = b1[tid];
        for (int k = 0; k < DD; ++k) a = fmaf(ge[k], W1[k * HC + tid], a);
        h1[tid] = fmaxf(a, 0.f);
    }
    __syncthreads();
    if (tid < HC) {
        float a = b2[tid];
        for (int k = 0; k < HC; ++k) a = fmaf(h1[k], W2[k * HC + tid], a);
        h2[tid] = fmaxf(a, 0.f);
    }
    __syncthreads();
    if (tid < 64) {
        float p = h2[tid] * W3[tid];
        #pragma unroll
        for (int off = 32; off; off >>= 1) p += __shfl_xor(p, off);
        if (tid == 0) value[g] = p + b3[0];
    }
}

// ---------------------------------------------------------------- actor MLP (edge/thread)
__device__ __forceinline__ void fma64(float* h, const float* __restrict__ wrow, float v) {
    const float4* w4 = (const float4*)wrow;
    #pragma unroll
    for (int c4 = 0; c4 < 16; ++c4) {
        float4 w = w4[c4];
        h[c4 * 4 + 0] = fmaf(v, w.x, h[c4 * 4 + 0]);
        h[c4 * 4 + 1] = fmaf(v, w.y, h[c4 * 4 + 1]);
        h[c4 * 4 + 2] = fmaf(v, w.z, h[c4 * 4 + 2]);
        h[c4 * 4 + 3] = fmaf(v, w.w, h[c4 * 4 + 3]);
    }
}

__global__ __launch_bounds__(256) void k_actor(const float* __restrict__ feats,
                                               const float* __restrict__ gemb,
                                               const int* __restrict__ esrc,
                                               const int* __restrict__ edst,
                                               const float* __restrict__ W1,
                                               const float* __restrict__ b1,
                                               const float* __restrict__ W2,
                                               const float* __restrict__ b2,
                                               const float* __restrict__ W3,
                                               const float* __restrict__ b3,
                                               float* __restrict__ logits) {
    int e = blockIdx.x * 256 + threadIdx.x;
    int g = blockIdx.x >> 6;               // E/256 = 64 blocks per graph (uniform)
    int s = esrc[e];
    int t = edst[e];

    float h1[HA];
    #pragma unroll
    for (int c = 0; c < HA; ++c) h1[c] = b1[c];

    // state part (wave-uniform): rows 0..31 of W1
    const float* geg = gemb + g * DD;
    for (int k = 0; k < DD; ++k) fma64(h1, W1 + k * HA, geg[k]);

    // feats[src]: rows 32..63
    const float4* fsp = (const float4*)(feats + s * DD);
    #pragma unroll
    for (int k4 = 0; k4 < DD / 4; ++k4) {
        float4 v = fsp[k4];
        fma64(h1, W1 + (DD + k4 * 4 + 0) * HA, v.x);
        fma64(h1, W1 + (DD + k4 * 4 + 1) * HA, v.y);
        fma64(h1, W1 + (DD + k4 * 4 + 2) * HA, v.z);
        fma64(h1, W1 + (DD + k4 * 4 + 3) * HA, v.w);
    }
    // feats[dst]: rows 64..95
    const float4* fdp = (const float4*)(feats + t * DD);
    #pragma unroll
    for (int k4 = 0; k4 < DD / 4; ++k4) {
        float4 v = fdp[k4];
        fma64(h1, W1 + (2 * DD + k4 * 4 + 0) * HA, v.x);
        fma64(h1, W1 + (2 * DD + k4 * 4 + 1) * HA, v.y);
        fma64(h1, W1 + (2 * DD + k4 * 4 + 2) * HA, v.z);
        fma64(h1, W1 + (2 * DD + k4 * 4 + 3) * HA, v.w);
    }
    #pragma unroll
    for (int c = 0; c < HA; ++c) h1[c] = fmaxf(h1[c], 0.f);

    float h2[HA];
    #pragma unroll
    for (int c = 0; c < HA; ++c) h2[c] = b2[c];
    #pragma unroll
    for (int k = 0; k < HA; ++k) fma64(h2, W2 + k * HA, h1[k]);

    float accv = b3[0];
    #pragma unroll
    for (int k = 0; k < HA; ++k) accv = fmaf(fmaxf(h2[k], 0.f), W3[k], accv);
    logits[e] = accv;
}

// ---------------------------------------------------------------- per-graph softmax
__global__ __launch_bounds__(256) void k_softmax(const float* __restrict__ logits,
                                                 float* __restrict__ pi) {
    int g = blockIdx.x;
    const float* lg = logits + g * EE;
    __shared__ float wred[4];
    __shared__ float bval;
    int tid = threadIdx.x;
    int wid = tid >> 6, lane = tid & 63;

    float m = -1e30f;
    for (int i = tid; i < EE; i += 256) m = fmaxf(m, lg[i]);
    #pragma unroll
    for (int off = 32; off; off >>= 1) m = fmaxf(m, __shfl_xor(m, off));
    if (lane == 0) wred[wid] = m;
    __syncthreads();
    if (tid == 0) bval = fmaxf(fmaxf(wred[0], wred[1]), fmaxf(wred[2], wred[3]));
    __syncthreads();
    float gm = bval;

    float ssum = 0.f;
    for (int i = tid; i < EE; i += 256) ssum += expf(lg[i] - gm);
    #pragma unroll
    for (int off = 32; off; off >>= 1) ssum += __shfl_xor(ssum, off);
    if (lane == 0) wred[wid] = ssum;
    __syncthreads();
    if (tid == 0) bval = wred[0] + wred[1] + wred[2] + wred[3];
    __syncthreads();
    float inv = 1.f / bval;
    for (int i = tid; i < EE; i += 256) pi[g * EE + i] = expf(lg[i] - gm) * inv;
}

// ---------------------------------------------------------------- launch
extern "C" void kernel_launch(void* const* d_in, const int* in_sizes, int n_in,
                              void* d_out, int out_size, void* d_ws, size_t ws_size,
                              hipStream_t stream) {
    const float* x      = (const float*)d_in[0];
    const int*   ei     = (const int*)d_in[1];
    const float* ginW   = (const float*)d_in[3];   // [L,M,D,D]
    const float* ginb   = (const float*)d_in[4];   // [L,M,D]
    const float* ging   = (const float*)d_in[5];   // [L,M-1,D]
    const float* ginbe  = (const float*)d_in[6];   // [L,M-1,D]
    const float* aW1 = (const float*)d_in[7];
    const float* ab1 = (const float*)d_in[8];
    const float* aW2 = (const float*)d_in[9];
    const float* ab2 = (const float*)d_in[10];
    const float* aW3 = (const float*)d_in[11];
    const float* ab3 = (const float*)d_in[12];
    const float* cW1 = (const float*)d_in[13];
    const float* cb1 = (const float*)d_in[14];
    const float* cW2 = (const float*)d_in[15];
    const float* cb2 = (const float*)d_in[16];
    const float* cW3 = (const float*)d_in[17];
    const float* cb3 = (const float*)d_in[18];

    const int* esrc = ei;
    const int* edst = ei + TOTE;

    float* ws     = (float*)d_ws;
    float* feats  = ws;                    // NTOT*DD
    float* ybuf   = ws + 1 * 1048576;      // NTOT*DD
    float* hbuf   = ws + 2 * 1048576;      // NTOT*DD
    float* logits = ws + 3 * 1048576;      // TOTE
    float* stats  = ws + 4 * 1048576;      // 6*64
    float* gemb   = stats + 384;           // BB*DD

    float* out_pi = (float*)d_out;
    float* out_v  = out_pi + TOTE;

    #define GW(l, i)  (ginW  + ((l) * 3 + (i)) * DD * DD)
    #define GB(l, i)  (ginb  + ((l) * 3 + (i)) * DD)
    #define GG(l, i)  (ging  + ((l) * 2 + (i)) * DD)
    #define GBE(l, i) (ginbe + ((l) * 2 + (i)) * DD)
    #define ST(i)     (stats + (i) * 64)

    k_zero<<<1, 384, 0, stream>>>(stats);

    // ---- layer 0 (input = x, y in ybuf)
    k_copy<<<NTOT * DD / 4 / 256, 256, 0, stream>>>((const float4*)x, (float4*)ybuf);
    k_agg<<<BB * AGG_SPLIT, 256, 0, stream>>>(x, esrc, edst, ybuf);
    k_mm_stats<<<NTOT / 8, 256, 0, stream>>>(ybuf, GW(0, 0), GB(0, 0), hbuf, ST(0));
    k_bnmm<<<NTOT / 8, 256, 0, stream>>>(hbuf, ST(0), GG(0, 0), GBE(0, 0),
                                         GW(0, 1), GB(0, 1), ybuf, nullptr, ST(1));
    k_bnmm<<<NTOT / 8, 256, 0, stream>>>(ybuf, ST(1), GG(0, 1), GBE(0, 1),
                                         GW(0, 2), GB(0, 2), feats, hbuf, nullptr);

    // ---- layer 1 (y in hbuf, pre-copied)
    k_agg<<<BB * AGG_SPLIT, 256, 0, stream>>>(feats, esrc, edst, hbuf);
    k_mm_stats<<<NTOT / 8, 256, 0, stream>>>(hbuf, GW(1, 0), GB(1, 0), ybuf, ST(2));
    k_bnmm<<<NTOT / 8, 256, 0, stream>>>(ybuf, ST(2), GG(1, 0), GBE(1, 0),
                                         GW(1, 1), GB(1, 1), hbuf, nullptr, ST(3));
    k_bnmm<<<NTOT / 8, 256, 0, stream>>>(hbuf, ST(3), GG(1, 1), GBE(1, 1),
                                         GW(1, 2), GB(1, 2), feats, ybuf, nullptr);

    // ---- layer 2 (y in ybuf, pre-copied)
    k_agg<<<BB * AGG_SPLIT, 256, 0, stream>>>(feats, esrc, edst, ybuf);
    k_mm_stats<<<NTOT / 8, 256, 0, stream>>>(ybuf, GW(2, 0), GB(2, 0), hbuf, ST(4));
    k_bnmm<<<NTOT / 8, 256, 0, stream>>>(hbuf, ST(4), GG(2, 0), GBE(2, 0),
                                         GW(2, 1), GB(2, 1), ybuf, nullptr, ST(5));
    k_bnmm<<<NTOT / 8, 256, 0, stream>>>(ybuf, ST(5), GG(2, 1), GBE(2, 1),
                                         GW(2, 2), GB(2, 2), feats, nullptr, nullptr);

    // ---- heads
    k_pool_critic<<<BB, 256, 0, stream>>>(feats, gemb, cW1, cb1, cW2, cb2, cW3, cb3, out_v);
    k_actor<<<TOTE / 256, 256, 0, stream>>>(feats, gemb, esrc, edst,
                                            aW1, ab1, aW2, ab2, aW3, ab3, logits);
    k_softmax<<<BB, 256, 0, stream>>>(logits, out_pi);

    #undef GW
    #undef GB
    #undef GG
    #undef GBE
    #undef ST
}

// Round 2
// 1407.070 us; speedup vs baseline: 1.6000x; 1.6000x over previous
//
#include <hip/hip_runtime.h>
#include <hip/hip_bf16.h>
#include <math.h>

// Problem constants (match reference)
#define BB    64          // graphs
#define NN    512         // nodes per graph
#define DD    32          // feature dim
#define EE    16384       // edges per graph
#define NTOT  32768       // B*N total nodes
#define TOTE  1048576     // B*E total edges
#define HA    64
#define HC    64
#define BN_EPS 1e-5f

typedef __attribute__((ext_vector_type(8))) short bf16x8;
typedef __attribute__((ext_vector_type(4))) float f32x4;

__device__ __forceinline__ short f2bf(float f) {
    union { __hip_bfloat16 h; short s; } u;
    u.h = __float2bfloat16(f);
    return u.s;
}

// ---------------------------------------------------------------- zero stats
__global__ void k_zero(float* __restrict__ stats) {
    if (threadIdx.x < 384) stats[threadIdx.x] = 0.f;
}

// ---------------------------------------------------------------- aggregation
// d-split LDS partial (16 KB -> high occupancy), atomic flush into zeroed y.
// y accumulates ONLY the neighbor sum; self term added in k_mm_stats.
__global__ __launch_bounds__(256) void k_agg(const float* __restrict__ feats,
                                             const int* __restrict__ esrc,
                                             const int* __restrict__ edst,
                                             float* __restrict__ y) {
    __shared__ float acc[NN * 8];   // 16 KB: 512 nodes x 8 feats
    int b = blockIdx.x;
    int g     = b >> 5;         // 64 graphs
    int rem   = b & 31;
    int dblk  = rem >> 3;       // 0..3 (which 8-feat slice)
    int chunk = rem & 7;        // 0..7 (2048-edge chunk)
    for (int i = threadIdx.x; i < NN * 8; i += 256) acc[i] = 0.f;
    __syncthreads();

    int dl   = threadIdx.x & 7;
    int slot = threadIdx.x >> 3;       // 32 slots
    int ebase = g * EE + chunk * 2048;
    int nbase = g << 9;
    int doff  = dblk * 8 + dl;
    for (int j = slot; j < 4096; j += 32) {   // 4096 edge-dirs
        int e = ebase + (j >> 1);
        int s = esrc[e];
        int t = edst[e];
        int u = (j & 1) ? t : s;   // value source
        int v = (j & 1) ? s : t;   // accumulate target
        atomicAdd(&acc[((v - nbase) << 3) + dl], feats[(u << 5) + doff]);
    }
    __syncthreads();
    int obase = (nbase << 5) + dblk * 8;
    for (int i = threadIdx.x; i < NN * 8; i += 256) {
        int n = i >> 3, d = i & 7;
        atomicAdd(&y[obase + (n << 5) + d], acc[i]);
    }
}

// ---------------------------------------------------------------- h = (X+AGG)@W + b, stats
__global__ __launch_bounds__(256) void k_mm_stats(const float* __restrict__ X,
                                                  const float* __restrict__ AGG,
                                                  const float* __restrict__ W,
                                                  const float* __restrict__ bias,
                                                  float* __restrict__ Hout,
                                                  float* __restrict__ stats) {
    __shared__ float Wsh[DD * DD];
    __shared__ float red[8][64];
    int tid = threadIdx.x;
    for (int i = tid; i < DD * DD; i += 256) Wsh[i] = W[i];
    __syncthreads();

    int c = tid & 31, rg = tid >> 5;
    float bcol = bias[c];
    float bsum = 0.f, bsq = 0.f;
    for (int rr = 0; rr < 8; ++rr) {
        int row = blockIdx.x * 64 + rg * 8 + rr;
        const float4* xr = (const float4*)(X + (row << 5));
        const float4* ar = (const float4*)(AGG + (row << 5));
        float accv = bcol;
        #pragma unroll
        for (int k4 = 0; k4 < 8; ++k4) {
            float4 xv = xr[k4];
            float4 av = ar[k4];
            int kb = k4 * 4;
            accv = fmaf(xv.x + av.x, Wsh[(kb + 0) * DD + c], accv);
            accv = fmaf(xv.y + av.y, Wsh[(kb + 1) * DD + c], accv);
            accv = fmaf(xv.z + av.z, Wsh[(kb + 2) * DD + c], accv);
            accv = fmaf(xv.w + av.w, Wsh[(kb + 3) * DD + c], accv);
        }
        Hout[(row << 5) + c] = accv;
        bsum += accv; bsq += accv * accv;
    }
    red[rg][c] = bsum;
    red[rg][32 + c] = bsq;
    __syncthreads();
    if (tid < 64) {
        float v = 0.f;
        #pragma unroll
        for (int i = 0; i < 8; ++i) v += red[i][tid];
        atomicAdd(&stats[tid], v);
    }
}

// ---------------------------------------------------------------- relu(bn(Hin)) @ W + b
__global__ __launch_bounds__(256) void k_bnmm(const float* __restrict__ Hin,
                                              const float* __restrict__ instats,
                                              const float* __restrict__ gamma,
                                              const float* __restrict__ beta,
                                              const float* __restrict__ W,
                                              const float* __restrict__ bias,
                                              float* __restrict__ Hout,
                                              float* __restrict__ outstats) {
    __shared__ float Wsh[DD * DD];
    __shared__ float As[DD], Cs[DD];
    __shared__ float red[8][64];
    int tid = threadIdx.x;
    for (int i = tid; i < DD * DD; i += 256) Wsh[i] = W[i];
    if (tid < DD) {
        float s  = instats[tid];
        float q  = instats[DD + tid];
        float mu = s * (1.f / NTOT);
        float var = q * (1.f / NTOT) - mu * mu;
        float a  = gamma[tid] * rsqrtf(var + BN_EPS);
        As[tid]  = a;
        Cs[tid]  = beta[tid] - mu * a;
    }
    __syncthreads();

    int c = tid & 31, rg = tid >> 5;
    float bcol = bias[c];
    float bsum = 0.f, bsq = 0.f;
    for (int rr = 0; rr < 8; ++rr) {
        int row = blockIdx.x * 64 + rg * 8 + rr;
        const float4* xr = (const float4*)(Hin + (row << 5));
        float accv = bcol;
        #pragma unroll
        for (int k4 = 0; k4 < 8; ++k4) {
            float4 xv = xr[k4];
            int kb = k4 * 4;
            float xn;
            xn = fmaxf(fmaf(xv.x, As[kb + 0], Cs[kb + 0]), 0.f);
            accv = fmaf(xn, Wsh[(kb + 0) * DD + c], accv);
            xn = fmaxf(fmaf(xv.y, As[kb + 1], Cs[kb + 1]), 0.f);
            accv = fmaf(xn, Wsh[(kb + 1) * DD + c], accv);
            xn = fmaxf(fmaf(xv.z, As[kb + 2], Cs[kb + 2]), 0.f);
            accv = fmaf(xn, Wsh[(kb + 2) * DD + c], accv);
            xn = fmaxf(fmaf(xv.w, As[kb + 3], Cs[kb + 3]), 0.f);
            accv = fmaf(xn, Wsh[(kb + 3) * DD + c], accv);
        }
        Hout[(row << 5) + c] = accv;
        bsum += accv; bsq += accv * accv;
    }
    if (outstats) {
        red[rg][c] = bsum;
        red[rg][32 + c] = bsq;
        __syncthreads();
        if (tid < 64) {
            float v = 0.f;
            #pragma unroll
            for (int i = 0; i < 8; ++i) v += red[i][tid];
            atomicAdd(&outstats[tid], v);
        }
    }
}

// ---------------------------------------------------------------- pool + critic
__global__ __launch_bounds__(256) void k_pool_critic(const float* __restrict__ feats,
                                                     float* __restrict__ gemb,
                                                     const float* __restrict__ W1,
                                                     const float* __restrict__ b1,
                                                     const float* __restrict__ W2,
                                                     const float* __restrict__ b2,
                                                     const float* __restrict__ W3,
                                                     const float* __restrict__ b3,
                                                     float* __restrict__ value) {
    int g = blockIdx.x;
    __shared__ float red[8][DD];
    __shared__ float ge[DD];
    __shared__ float h1[HC];
    __shared__ float h2[HC];
    int tid = threadIdx.x;
    int d = tid & 31, grp = tid >> 5;
    float s = 0.f;
    const float* fg = feats + g * NN * DD;
    for (int n = grp; n < NN; n += 8) s += fg[n * DD + d];
    red[grp][d] = s;
    __syncthreads();
    if (tid < DD) {
        float t = 0.f;
        #pragma unroll
        for (int i = 0; i < 8; ++i) t += red[i][tid];
        t *= (1.f / NN);
        ge[tid] = t;
        gemb[g * DD + tid] = t;
    }
    __syncthreads();
    if (tid < HC) {
        float a = b1[tid];
        for (int k = 0; k < DD; ++k) a = fmaf(ge[k], W1[k * HC + tid], a);
        h1[tid] = fmaxf(a, 0.f);
    }
    __syncthreads();
    if (tid < HC) {
        float a = b2[tid];
        for (int k = 0; k < HC; ++k) a = fmaf(h1[k], W2[k * HC + tid], a);
        h2[tid] = fmaxf(a, 0.f);
    }
    __syncthreads();
    if (tid < 64) {
        float p = h2[tid] * W3[tid];
        #pragma unroll
        for (int off = 32; off; off >>= 1) p += __shfl_xor(p, off);
        if (tid == 0) value[g] = p + b3[0];
    }
}

// ---------------------------------------------------------------- gW[g][c] = b1[c] + gemb[g]@W1a
__global__ void k_gembW(const float* __restrict__ gemb,
                        const float* __restrict__ W1,
                        const float* __restrict__ b1,
                        float* __restrict__ gW) {
    int idx = blockIdx.x * 256 + threadIdx.x;   // 4096 = 64 graphs x 64 cols
    int g = idx >> 6, c = idx & 63;
    float a = b1[c];
    #pragma unroll 4
    for (int k = 0; k < DD; ++k) a = fmaf(gemb[(g << 5) + k], W1[k * HA + c], a);
    gW[idx] = a;
}

// ---------------------------------------------------------------- per-node actor precompute
// pre_s[n] = feats[n]@W1b + gW[g(n)]  (gW includes b1);  pre_t[n] = feats[n]@W1c
__global__ __launch_bounds__(256) void k_pre(const float* __restrict__ feats,
                                             const float* __restrict__ W1,
                                             const float* __restrict__ gW,
                                             float* __restrict__ pre_s,
                                             float* __restrict__ pre_t) {
    __shared__ float Wb[DD * HA];   // 8 KB
    __shared__ float Wc[DD * HA];   // 8 KB
    int tid = threadIdx.x;
    for (int i = tid; i < DD * HA; i += 256) {
        Wb[i] = W1[DD * HA + i];       // rows 32..63 of W1
        Wc[i] = W1[2 * DD * HA + i];   // rows 64..95
    }
    __syncthreads();
    int c = tid & 63, rl = tid >> 6;
    for (int rr = 0; rr < 4; ++rr) {
        int row = blockIdx.x * 16 + rr * 4 + rl;
        const float4* fr = (const float4*)(feats + (row << 5));
        float as = gW[((row >> 9) << 6) + c];
        float at = 0.f;
        #pragma unroll
        for (int k4 = 0; k4 < 8; ++k4) {
            float4 f = fr[k4];
            int kb = k4 * 4;
            as = fmaf(f.x, Wb[(kb + 0) * HA + c], as); at = fmaf(f.x, Wc[(kb + 0) * HA + c], at);
            as = fmaf(f.y, Wb[(kb + 1) * HA + c], as); at = fmaf(f.y, Wc[(kb + 1) * HA + c], at);
            as = fmaf(f.z, Wb[(kb + 2) * HA + c], as); at = fmaf(f.z, Wc[(kb + 2) * HA + c], at);
            as = fmaf(f.w, Wb[(kb + 3) * HA + c], as); at = fmaf(f.w, Wc[(kb + 3) * HA + c], at);
        }
        pre_s[(row << 6) + c] = as;
        pre_t[(row << 6) + c] = at;
    }
}

// ---------------------------------------------------------------- pack W2 into MFMA B-fragments
// frag f = nt*2 + kh; element j of lane l <-> W2[kh*32 + (l>>4)*8 + j][nt*16 + (l&15)]
__global__ void k_packW2(const float* __restrict__ W2, short* __restrict__ wfrag) {
    int lane = threadIdx.x;
    if (lane < 64) {
        #pragma unroll
        for (int f = 0; f < 8; ++f) {
            int nt = f >> 1, kh = f & 1;
            int n = nt * 16 + (lane & 15);
            int kbase = kh * 32 + (lane >> 4) * 8;
            #pragma unroll
            for (int j = 0; j < 8; ++j)
                wfrag[(f * 64 + lane) * 8 + j] = f2bf(W2[(kbase + j) * HA + n]);
        }
    }
}

// ---------------------------------------------------------------- actor: MFMA over edges
// wave = 16 edges. h1 = relu(pre_s[s]+pre_t[t]) built directly in A-fragment
// layout (lane l: row l&15, k = (l>>4)*8+j), 8 MFMAs (4 n-tiles x K=64),
// fused +b2, relu, W3-dot, 16-lane reduce, float4 store of 16 logits.
__global__ __launch_bounds__(256) void k_actor(const float* __restrict__ pre_s,
                                               const float* __restrict__ pre_t,
                                               const int* __restrict__ esrc,
                                               const int* __restrict__ edst,
                                               const short* __restrict__ wfrag,
                                               const float* __restrict__ b2,
                                               const float* __restrict__ b3,
                                               const float* __restrict__ W3,
                                               float* __restrict__ logits) {
    int lane = threadIdx.x & 63;
    int wid  = (blockIdx.x * 256 + threadIdx.x) >> 6;   // 0..8191
    int r16  = lane & 15;
    int kg   = lane >> 4;          // k-group 0..3
    int kg2  = kg * 2;

    const bf16x8* wf = (const bf16x8*)wfrag;
    bf16x8 bw0 = wf[0 * 64 + lane];
    bf16x8 bw1 = wf[1 * 64 + lane];
    bf16x8 bw2 = wf[2 * 64 + lane];
    bf16x8 bw3 = wf[3 * 64 + lane];
    bf16x8 bw4 = wf[4 * 64 + lane];
    bf16x8 bw5 = wf[5 * 64 + lane];
    bf16x8 bw6 = wf[6 * 64 + lane];
    bf16x8 bw7 = wf[7 * 64 + lane];

    float b2c0 = b2[r16],      b2c1 = b2[16 + r16];
    float b2c2 = b2[32 + r16], b2c3 = b2[48 + r16];
    float w3c0 = W3[r16],      w3c1 = W3[16 + r16];
    float w3c2 = W3[32 + r16], w3c3 = W3[48 + r16];
    float b3v = b3[0];

    for (int it = 0; it < 8; ++it) {
        int tile = wid * 8 + it;            // 65536 tiles of 16 edges
        int e = (tile << 4) + r16;
        int s = esrc[e];
        int t = edst[e];
        const float4* ps = (const float4*)(pre_s + (s << 6));
        const float4* pt = (const float4*)(pre_t + (t << 6));
        float4 s0 = ps[kg2], s1 = ps[kg2 + 1], s2 = ps[kg2 + 8], s3 = ps[kg2 + 9];
        float4 t0 = pt[kg2], t1 = pt[kg2 + 1], t2 = pt[kg2 + 8], t3 = pt[kg2 + 9];

        bf16x8 a0, a1;
        a0[0] = f2bf(fmaxf(s0.x + t0.x, 0.f));
        a0[1] = f2bf(fmaxf(s0.y + t0.y, 0.f));
        a0[2] = f2bf(fmaxf(s0.z + t0.z, 0.f));
        a0[3] = f2bf(fmaxf(s0.w + t0.w, 0.f));
        a0[4] = f2bf(fmaxf(s1.x + t1.x, 0.f));
        a0[5] = f2bf(fmaxf(s1.y + t1.y, 0.f));
        a0[6] = f2bf(fmaxf(s1.z + t1.z, 0.f));
        a0[7] = f2bf(fmaxf(s1.w + t1.w, 0.f));
        a1[0] = f2bf(fmaxf(s2.x + t2.x, 0.f));
        a1[1] = f2bf(fmaxf(s2.y + t2.y, 0.f));
        a1[2] = f2bf(fmaxf(s2.z + t2.z, 0.f));
        a1[3] = f2bf(fmaxf(s2.w + t2.w, 0.f));
        a1[4] = f2bf(fmaxf(s3.x + t3.x, 0.f));
        a1[5] = f2bf(fmaxf(s3.y + t3.y, 0.f));
        a1[6] = f2bf(fmaxf(s3.z + t3.z, 0.f));
        a1[7] = f2bf(fmaxf(s3.w + t3.w, 0.f));

        f32x4 acc0 = {0.f, 0.f, 0.f, 0.f};
        f32x4 acc1 = {0.f, 0.f, 0.f, 0.f};
        f32x4 acc2 = {0.f, 0.f, 0.f, 0.f};
        f32x4 acc3 = {0.f, 0.f, 0.f, 0.f};
        acc0 = __builtin_amdgcn_mfma_f32_16x16x32_bf16(a0, bw0, acc0, 0, 0, 0);
        acc0 = __builtin_amdgcn_mfma_f32_16x16x32_bf16(a1, bw1, acc0, 0, 0, 0);
        acc1 = __builtin_amdgcn_mfma_f32_16x16x32_bf16(a0, bw2, acc1, 0, 0, 0);
        acc1 = __builtin_amdgcn_mfma_f32_16x16x32_bf16(a1, bw3, acc1, 0, 0, 0);
        acc2 = __builtin_amdgcn_mfma_f32_16x16x32_bf16(a0, bw4, acc2, 0, 0, 0);
        acc2 = __builtin_amdgcn_mfma_f32_16x16x32_bf16(a1, bw5, acc2, 0, 0, 0);
        acc3 = __builtin_amdgcn_mfma_f32_16x16x32_bf16(a0, bw6, acc3, 0, 0, 0);
        acc3 = __builtin_amdgcn_mfma_f32_16x16x32_bf16(a1, bw7, acc3, 0, 0, 0);

        // h2 = relu(acc + b2); partial logit = sum_nt h2*W3
        float p0 = fmaxf(acc0[0] + b2c0, 0.f) * w3c0 + fmaxf(acc1[0] + b2c1, 0.f) * w3c1
                 + fmaxf(acc2[0] + b2c2, 0.f) * w3c2 + fmaxf(acc3[0] + b2c3, 0.f) * w3c3;
        float p1 = fmaxf(acc0[1] + b2c0, 0.f) * w3c0 + fmaxf(acc1[1] + b2c1, 0.f) * w3c1
                 + fmaxf(acc2[1] + b2c2, 0.f) * w3c2 + fmaxf(acc3[1] + b2c3, 0.f) * w3c3;
        float p2 = fmaxf(acc0[2] + b2c0, 0.f) * w3c0 + fmaxf(acc1[2] + b2c1, 0.f) * w3c1
                 + fmaxf(acc2[2] + b2c2, 0.f) * w3c2 + fmaxf(acc3[2] + b2c3, 0.f) * w3c3;
        float p3 = fmaxf(acc0[3] + b2c0, 0.f) * w3c0 + fmaxf(acc1[3] + b2c1, 0.f) * w3c1
                 + fmaxf(acc2[3] + b2c2, 0.f) * w3c2 + fmaxf(acc3[3] + b2c3, 0.f) * w3c3;

        // reduce over the 16 lanes of each k-group (cols)
        #pragma unroll
        for (int m = 1; m < 16; m <<= 1) {
            p0 += __shfl_xor(p0, m);
            p1 += __shfl_xor(p1, m);
            p2 += __shfl_xor(p2, m);
            p3 += __shfl_xor(p3, m);
        }
        if (r16 == 0) {
            float4 o;
            o.x = p0 + b3v; o.y = p1 + b3v; o.z = p2 + b3v; o.w = p3 + b3v;
            ((float4*)(logits + (tile << 4)))[kg] = o;   // rows kg*4..kg*4+3
        }
    }
}

// ---------------------------------------------------------------- per-graph softmax
__global__ __launch_bounds__(256) void k_softmax(const float* __restrict__ logits,
                                                 float* __restrict__ pi) {
    int g = blockIdx.x;
    const float* lg = logits + g * EE;
    __shared__ float wred[4];
    __shared__ float bval;
    int tid = threadIdx.x;
    int wid = tid >> 6, lane = tid & 63;

    float m = -1e30f;
    for (int i = tid; i < EE; i += 256) m = fmaxf(m, lg[i]);
    #pragma unroll
    for (int off = 32; off; off >>= 1) m = fmaxf(m, __shfl_xor(m, off));
    if (lane == 0) wred[wid] = m;
    __syncthreads();
    if (tid == 0) bval = fmaxf(fmaxf(wred[0], wred[1]), fmaxf(wred[2], wred[3]));
    __syncthreads();
    float gm = bval;

    float ssum = 0.f;
    for (int i = tid; i < EE; i += 256) ssum += expf(lg[i] - gm);
    #pragma unroll
    for (int off = 32; off; off >>= 1) ssum += __shfl_xor(ssum, off);
    if (lane == 0) wred[wid] = ssum;
    __syncthreads();
    if (tid == 0) bval = wred[0] + wred[1] + wred[2] + wred[3];
    __syncthreads();
    float inv = 1.f / bval;
    for (int i = tid; i < EE; i += 256) pi[g * EE + i] = expf(lg[i] - gm) * inv;
}

// ---------------------------------------------------------------- launch
extern "C" void kernel_launch(void* const* d_in, const int* in_sizes, int n_in,
                              void* d_out, int out_size, void* d_ws, size_t ws_size,
                              hipStream_t stream) {
    const float* x      = (const float*)d_in[0];
    const int*   ei     = (const int*)d_in[1];
    const float* ginW   = (const float*)d_in[3];   // [L,M,D,D]
    const float* ginb   = (const float*)d_in[4];   // [L,M,D]
    const float* ging   = (const float*)d_in[5];   // [L,M-1,D]
    const float* ginbe  = (const float*)d_in[6];   // [L,M-1,D]
    const float* aW1 = (const float*)d_in[7];
    const float* ab1 = (const float*)d_in[8];
    const float* aW2 = (const float*)d_in[9];
    const float* ab2 = (const float*)d_in[10];
    const float* aW3 = (const float*)d_in[11];
    const float* ab3 = (const float*)d_in[12];
    const float* cW1 = (const float*)d_in[13];
    const float* cb1 = (const float*)d_in[14];
    const float* cW2 = (const float*)d_in[15];
    const float* cb2 = (const float*)d_in[16];
    const float* cW3 = (const float*)d_in[17];
    const float* cb3 = (const float*)d_in[18];

    const int* esrc = ei;
    const int* edst = ei + TOTE;

    // workspace layout (floats): w0..w3 feat temps, pre_s, small area.
    // pre_t aliases w0+w1, logits aliases w3 (both free after GIN layers).
    float* ws     = (float*)d_ws;
    float* w0     = ws;                    // 1M floats
    float* w1     = ws + 1 * 1048576;
    float* w2     = ws + 2 * 1048576;
    float* w3     = ws + 3 * 1048576;
    float* pre_s  = ws + 4 * 1048576;      // 2M floats
    float* small  = ws + 6 * 1048576;
    float* pre_t  = w0;                    // 2M floats (w0+w1)
    float* logits = w3;                    // 1M floats

    float* stats  = small;                 // 6 x 64
    float* gemb   = small + 512;           // 64 x 32
    float* gW     = small + 2560;          // 64 x 64
    short* wfrag  = (short*)(small + 6656);// 8 x 64 x 8 bf16

    float* out_pi = (float*)d_out;
    float* out_v  = out_pi + TOTE;

    #define GW(l, i)  (ginW  + ((l) * 3 + (i)) * DD * DD)
    #define GB(l, i)  (ginb  + ((l) * 3 + (i)) * DD)
    #define GG(l, i)  (ging  + ((l) * 2 + (i)) * DD)
    #define GBE(l, i) (ginbe + ((l) * 2 + (i)) * DD)
    #define ST(i)     (stats + (i) * 64)

    k_zero<<<1, 384, 0, stream>>>(stats);
    k_packW2<<<1, 64, 0, stream>>>(aW2, wfrag);

    // ---- layer 0 (input = x)
    hipMemsetAsync(w0, 0, NTOT * DD * sizeof(float), stream);
    k_agg<<<BB * 32, 256, 0, stream>>>(x, esrc, edst, w0);
    k_mm_stats<<<NTOT / 64, 256, 0, stream>>>(x, w0, GW(0, 0), GB(0, 0), w1, ST(0));
    k_bnmm<<<NTOT / 64, 256, 0, stream>>>(w1, ST(0), GG(0, 0), GBE(0, 0),
                                          GW(0, 1), GB(0, 1), w0, ST(1));
    k_bnmm<<<NTOT / 64, 256, 0, stream>>>(w0, ST(1), GG(0, 1), GBE(0, 1),
                                          GW(0, 2), GB(0, 2), w2, nullptr);

    // ---- layer 1 (feats = w2)
    hipMemsetAsync(w0, 0, NTOT * DD * sizeof(float), stream);
    k_agg<<<BB * 32, 256, 0, stream>>>(w2, esrc, edst, w0);
    k_mm_stats<<<NTOT / 64, 256, 0, stream>>>(w2, w0, GW(1, 0), GB(1, 0), w1, ST(2));
    k_bnmm<<<NTOT / 64, 256, 0, stream>>>(w1, ST(2), GG(1, 0), GBE(1, 0),
                                          GW(1, 1), GB(1, 1), w0, ST(3));
    k_bnmm<<<NTOT / 64, 256, 0, stream>>>(w0, ST(3), GG(1, 1), GBE(1, 1),
                                          GW(1, 2), GB(1, 2), w3, nullptr);

    // ---- layer 2 (feats = w3)
    hipMemsetAsync(w0, 0, NTOT * DD * sizeof(float), stream);
    k_agg<<<BB * 32, 256, 0, stream>>>(w3, esrc, edst, w0);
    k_mm_stats<<<NTOT / 64, 256, 0, stream>>>(w3, w0, GW(2, 0), GB(2, 0), w1, ST(4));
    k_bnmm<<<NTOT / 64, 256, 0, stream>>>(w1, ST(4), GG(2, 0), GBE(2, 0),
                                          GW(2, 1), GB(2, 1), w0, ST(5));
    k_bnmm<<<NTOT / 64, 256, 0, stream>>>(w0, ST(5), GG(2, 1), GBE(2, 1),
                                          GW(2, 2), GB(2, 2), w2, nullptr);
    // final feats in w2

    // ---- heads
    k_pool_critic<<<BB, 256, 0, stream>>>(w2, gemb, cW1, cb1, cW2, cb2, cW3, cb3, out_v);
    k_gembW<<<16, 256, 0, stream>>>(gemb, aW1, ab1, gW);
    k_pre<<<NTOT / 16, 256, 0, stream>>>(w2, aW1, gW, pre_s, pre_t);
    k_actor<<<2048, 256, 0, stream>>>(pre_s, pre_t, esrc, edst, wfrag,
                                      ab2, ab3, aW3, logits);
    k_softmax<<<BB, 256, 0, stream>>>(logits, out_pi);

    #undef GW
    #undef GB
    #undef GG
    #undef GBE
    #undef ST
}

// Round 3
// 585.048 us; speedup vs baseline: 3.8482x; 2.4050x over previous
//
#include <hip/hip_runtime.h>
#include <hip/hip_bf16.h>
#include <math.h>

// Problem constants (match reference)
#define BB    64          // graphs
#define NN    512         // nodes per graph
#define DD    32          // feature dim
#define EE    16384       // edges per graph
#define NTOT  32768       // B*N total nodes
#define TOTE  1048576     // B*E total edges
#define NDIR  2097152     // 2*TOTE edge-dirs
#define HA    64
#define HC    64
#define BN_EPS 1e-5f

typedef __attribute__((ext_vector_type(8))) short bf16x8;
typedef __attribute__((ext_vector_type(4))) float f32x4;

__device__ __forceinline__ short f2bf(float f) {
    union { __hip_bfloat16 h; short s; } u;
    u.h = __float2bfloat16(f);
    return u.s;
}

// ---------------------------------------------------------------- zero stats
__global__ void k_zero(float* __restrict__ stats) {
    if (threadIdx.x < 384) stats[threadIdx.x] = 0.f;
}

// ================================================================ CSR build
// (edge_index is layer-invariant: build once, reuse for all 3 aggregations)

// in-degree histogram over both edge directions
__global__ __launch_bounds__(256) void k_hist(const int* __restrict__ esrc,
                                              const int* __restrict__ edst,
                                              int* __restrict__ cnt) {
    int e = blockIdx.x * 256 + threadIdx.x;
    int s = esrc[e];
    int t = edst[e];
    atomicAdd(&cnt[t], 1);
    atomicAdd(&cnt[s], 1);
}

// per-graph exclusive scan of 512 counts; global base = g*32768 (each graph
// has exactly 2*E = 32768 dirs). off[32768] = NDIR sentinel.
__global__ __launch_bounds__(512) void k_scan(const int* __restrict__ cnt,
                                              int* __restrict__ off,
                                              int* __restrict__ cursor) {
    __shared__ int buf0[512], buf1[512];
    int g = blockIdx.x, tid = threadIdx.x;
    int me = cnt[g * 512 + tid];
    buf0[tid] = me;
    __syncthreads();
    int* s = buf0; int* d = buf1;
    for (int dd = 1; dd < 512; dd <<= 1) {
        d[tid] = s[tid] + (tid >= dd ? s[tid - dd] : 0);
        __syncthreads();
        int* tmp = s; s = d; d = tmp;
    }
    int excl = s[tid] - me;
    int val = g * 32768 + excl;
    off[g * 512 + tid] = val;
    cursor[g * 512 + tid] = val;
    if (g == 0 && tid == 0) off[NTOT] = NDIR;
}

// scatter neighbor ids into CSR slots
__global__ __launch_bounds__(256) void k_scatter(const int* __restrict__ esrc,
                                                 const int* __restrict__ edst,
                                                 int* __restrict__ cursor,
                                                 int* __restrict__ nbr) {
    int e = blockIdx.x * 256 + threadIdx.x;
    int s = esrc[e];
    int t = edst[e];
    nbr[atomicAdd(&cursor[t], 1)] = s;
    nbr[atomicAdd(&cursor[s], 1)] = t;
}

// ---------------------------------------------------------------- CSR aggregation
// y[v] = feats[v] + sum_{u in nbr(v)} feats[u].  One 8-lane group per node,
// float4 per lane -> every neighbor read is a full coalesced 128B row.
// No atomics, no LDS, tiny VGPR -> max occupancy, register accumulation.
__global__ __launch_bounds__(256) void k_aggc(const float* __restrict__ feats,
                                              const int* __restrict__ off,
                                              const int* __restrict__ nbr,
                                              float* __restrict__ y) {
    int v  = blockIdx.x * 32 + (threadIdx.x >> 3);
    int dl = threadIdx.x & 7;
    const float4* f4 = (const float4*)feats;
    float4 acc = f4[v * 8 + dl];          // self term
    int j  = off[v];
    int e  = off[v + 1];
    // unrolled-by-2 with index prefetch for ILP
    for (; j + 1 < e; j += 2) {
        int u0 = nbr[j], u1 = nbr[j + 1];
        float4 a = f4[u0 * 8 + dl];
        float4 b = f4[u1 * 8 + dl];
        acc.x += a.x + b.x; acc.y += a.y + b.y;
        acc.z += a.z + b.z; acc.w += a.w + b.w;
    }
    if (j < e) {
        float4 a = f4[nbr[j] * 8 + dl];
        acc.x += a.x; acc.y += a.y; acc.z += a.z; acc.w += a.w;
    }
    ((float4*)y)[v * 8 + dl] = acc;
}

// ---------------------------------------------------------------- h = Y@W + b, stats
__global__ __launch_bounds__(256) void k_mm_stats(const float* __restrict__ X,
                                                  const float* __restrict__ W,
                                                  const float* __restrict__ bias,
                                                  float* __restrict__ Hout,
                                                  float* __restrict__ stats) {
    __shared__ float Wsh[DD * DD];
    __shared__ float red[8][64];
    int tid = threadIdx.x;
    for (int i = tid; i < DD * DD; i += 256) Wsh[i] = W[i];
    __syncthreads();

    int c = tid & 31, rg = tid >> 5;
    float bcol = bias[c];
    float bsum = 0.f, bsq = 0.f;
    for (int rr = 0; rr < 8; ++rr) {
        int row = blockIdx.x * 64 + rg * 8 + rr;
        const float4* xr = (const float4*)(X + (row << 5));
        float accv = bcol;
        #pragma unroll
        for (int k4 = 0; k4 < 8; ++k4) {
            float4 xv = xr[k4];
            int kb = k4 * 4;
            accv = fmaf(xv.x, Wsh[(kb + 0) * DD + c], accv);
            accv = fmaf(xv.y, Wsh[(kb + 1) * DD + c], accv);
            accv = fmaf(xv.z, Wsh[(kb + 2) * DD + c], accv);
            accv = fmaf(xv.w, Wsh[(kb + 3) * DD + c], accv);
        }
        Hout[(row << 5) + c] = accv;
        bsum += accv; bsq += accv * accv;
    }
    red[rg][c] = bsum;
    red[rg][32 + c] = bsq;
    __syncthreads();
    if (tid < 64) {
        float v = 0.f;
        #pragma unroll
        for (int i = 0; i < 8; ++i) v += red[i][tid];
        atomicAdd(&stats[tid], v);
    }
}

// ---------------------------------------------------------------- relu(bn(Hin)) @ W + b
__global__ __launch_bounds__(256) void k_bnmm(const float* __restrict__ Hin,
                                              const float* __restrict__ instats,
                                              const float* __restrict__ gamma,
                                              const float* __restrict__ beta,
                                              const float* __restrict__ W,
                                              const float* __restrict__ bias,
                                              float* __restrict__ Hout,
                                              float* __restrict__ outstats) {
    __shared__ float Wsh[DD * DD];
    __shared__ float As[DD], Cs[DD];
    __shared__ float red[8][64];
    int tid = threadIdx.x;
    for (int i = tid; i < DD * DD; i += 256) Wsh[i] = W[i];
    if (tid < DD) {
        float s  = instats[tid];
        float q  = instats[DD + tid];
        float mu = s * (1.f / NTOT);
        float var = q * (1.f / NTOT) - mu * mu;
        float a  = gamma[tid] * rsqrtf(var + BN_EPS);
        As[tid]  = a;
        Cs[tid]  = beta[tid] - mu * a;
    }
    __syncthreads();

    int c = tid & 31, rg = tid >> 5;
    float bcol = bias[c];
    float bsum = 0.f, bsq = 0.f;
    for (int rr = 0; rr < 8; ++rr) {
        int row = blockIdx.x * 64 + rg * 8 + rr;
        const float4* xr = (const float4*)(Hin + (row << 5));
        float accv = bcol;
        #pragma unroll
        for (int k4 = 0; k4 < 8; ++k4) {
            float4 xv = xr[k4];
            int kb = k4 * 4;
            float xn;
            xn = fmaxf(fmaf(xv.x, As[kb + 0], Cs[kb + 0]), 0.f);
            accv = fmaf(xn, Wsh[(kb + 0) * DD + c], accv);
            xn = fmaxf(fmaf(xv.y, As[kb + 1], Cs[kb + 1]), 0.f);
            accv = fmaf(xn, Wsh[(kb + 1) * DD + c], accv);
            xn = fmaxf(fmaf(xv.z, As[kb + 2], Cs[kb + 2]), 0.f);
            accv = fmaf(xn, Wsh[(kb + 2) * DD + c], accv);
            xn = fmaxf(fmaf(xv.w, As[kb + 3], Cs[kb + 3]), 0.f);
            accv = fmaf(xn, Wsh[(kb + 3) * DD + c], accv);
        }
        Hout[(row << 5) + c] = accv;
        bsum += accv; bsq += accv * accv;
    }
    if (outstats) {
        red[rg][c] = bsum;
        red[rg][32 + c] = bsq;
        __syncthreads();
        if (tid < 64) {
            float v = 0.f;
            #pragma unroll
            for (int i = 0; i < 8; ++i) v += red[i][tid];
            atomicAdd(&outstats[tid], v);
        }
    }
}

// ---------------------------------------------------------------- pool + critic
__global__ __launch_bounds__(256) void k_pool_critic(const float* __restrict__ feats,
                                                     float* __restrict__ gemb,
                                                     const float* __restrict__ W1,
                                                     const float* __restrict__ b1,
                                                     const float* __restrict__ W2,
                                                     const float* __restrict__ b2,
                                                     const float* __restrict__ W3,
                                                     const float* __restrict__ b3,
                                                     float* __restrict__ value) {
    int g = blockIdx.x;
    __shared__ float red[8][DD];
    __shared__ float ge[DD];
    __shared__ float h1[HC];
    __shared__ float h2[HC];
    int tid = threadIdx.x;
    int d = tid & 31, grp = tid >> 5;
    float s = 0.f;
    const float* fg = feats + g * NN * DD;
    for (int n = grp; n < NN; n += 8) s += fg[n * DD + d];
    red[grp][d] = s;
    __syncthreads();
    if (tid < DD) {
        float t = 0.f;
        #pragma unroll
        for (int i = 0; i < 8; ++i) t += red[i][tid];
        t *= (1.f / NN);
        ge[tid] = t;
        gemb[g * DD + tid] = t;
    }
    __syncthreads();
    if (tid < HC) {
        float a = b1[tid];
        for (int k = 0; k < DD; ++k) a = fmaf(ge[k], W1[k * HC + tid], a);
        h1[tid] = fmaxf(a, 0.f);
    }
    __syncthreads();
    if (tid < HC) {
        float a = b2[tid];
        for (int k = 0; k < HC; ++k) a = fmaf(h1[k], W2[k * HC + tid], a);
        h2[tid] = fmaxf(a, 0.f);
    }
    __syncthreads();
    if (tid < 64) {
        float p = h2[tid] * W3[tid];
        #pragma unroll
        for (int off = 32; off; off >>= 1) p += __shfl_xor(p, off);
        if (tid == 0) value[g] = p + b3[0];
    }
}

// ---------------------------------------------------------------- gW[g][c] = b1[c] + gemb[g]@W1a
__global__ void k_gembW(const float* __restrict__ gemb,
                        const float* __restrict__ W1,
                        const float* __restrict__ b1,
                        float* __restrict__ gW) {
    int idx = blockIdx.x * 256 + threadIdx.x;   // 4096 = 64 graphs x 64 cols
    int g = idx >> 6, c = idx & 63;
    float a = b1[c];
    #pragma unroll 4
    for (int k = 0; k < DD; ++k) a = fmaf(gemb[(g << 5) + k], W1[k * HA + c], a);
    gW[idx] = a;
}

// ---------------------------------------------------------------- per-node actor precompute
// pre_s[n] = feats[n]@W1b + gW[g(n)]  (gW includes b1);  pre_t[n] = feats[n]@W1c
__global__ __launch_bounds__(256) void k_pre(const float* __restrict__ feats,
                                             const float* __restrict__ W1,
                                             const float* __restrict__ gW,
                                             float* __restrict__ pre_s,
                                             float* __restrict__ pre_t) {
    __shared__ float Wb[DD * HA];   // 8 KB
    __shared__ float Wc[DD * HA];   // 8 KB
    int tid = threadIdx.x;
    for (int i = tid; i < DD * HA; i += 256) {
        Wb[i] = W1[DD * HA + i];       // rows 32..63 of W1
        Wc[i] = W1[2 * DD * HA + i];   // rows 64..95
    }
    __syncthreads();
    int c = tid & 63, rl = tid >> 6;
    for (int rr = 0; rr < 4; ++rr) {
        int row = blockIdx.x * 16 + rr * 4 + rl;
        const float4* fr = (const float4*)(feats + (row << 5));
        float as = gW[((row >> 9) << 6) + c];
        float at = 0.f;
        #pragma unroll
        for (int k4 = 0; k4 < 8; ++k4) {
            float4 f = fr[k4];
            int kb = k4 * 4;
            as = fmaf(f.x, Wb[(kb + 0) * HA + c], as); at = fmaf(f.x, Wc[(kb + 0) * HA + c], at);
            as = fmaf(f.y, Wb[(kb + 1) * HA + c], as); at = fmaf(f.y, Wc[(kb + 1) * HA + c], at);
            as = fmaf(f.z, Wb[(kb + 2) * HA + c], as); at = fmaf(f.z, Wc[(kb + 2) * HA + c], at);
            as = fmaf(f.w, Wb[(kb + 3) * HA + c], as); at = fmaf(f.w, Wc[(kb + 3) * HA + c], at);
        }
        pre_s[(row << 6) + c] = as;
        pre_t[(row << 6) + c] = at;
    }
}

// ---------------------------------------------------------------- pack W2 into MFMA B-fragments
__global__ void k_packW2(const float* __restrict__ W2, short* __restrict__ wfrag) {
    int lane = threadIdx.x;
    if (lane < 64) {
        #pragma unroll
        for (int f = 0; f < 8; ++f) {
            int nt = f >> 1, kh = f & 1;
            int n = nt * 16 + (lane & 15);
            int kbase = kh * 32 + (lane >> 4) * 8;
            #pragma unroll
            for (int j = 0; j < 8; ++j)
                wfrag[(f * 64 + lane) * 8 + j] = f2bf(W2[(kbase + j) * HA + n]);
        }
    }
}

// ---------------------------------------------------------------- actor: MFMA over edges
__global__ __launch_bounds__(256) void k_actor(const float* __restrict__ pre_s,
                                               const float* __restrict__ pre_t,
                                               const int* __restrict__ esrc,
                                               const int* __restrict__ edst,
                                               const short* __restrict__ wfrag,
                                               const float* __restrict__ b2,
                                               const float* __restrict__ b3,
                                               const float* __restrict__ W3,
                                               float* __restrict__ logits) {
    int lane = threadIdx.x & 63;
    int wid  = (blockIdx.x * 256 + threadIdx.x) >> 6;   // 0..8191
    int r16  = lane & 15;
    int kg   = lane >> 4;          // k-group 0..3
    int kg2  = kg * 2;

    const bf16x8* wf = (const bf16x8*)wfrag;
    bf16x8 bw0 = wf[0 * 64 + lane];
    bf16x8 bw1 = wf[1 * 64 + lane];
    bf16x8 bw2 = wf[2 * 64 + lane];
    bf16x8 bw3 = wf[3 * 64 + lane];
    bf16x8 bw4 = wf[4 * 64 + lane];
    bf16x8 bw5 = wf[5 * 64 + lane];
    bf16x8 bw6 = wf[6 * 64 + lane];
    bf16x8 bw7 = wf[7 * 64 + lane];

    float b2c0 = b2[r16],      b2c1 = b2[16 + r16];
    float b2c2 = b2[32 + r16], b2c3 = b2[48 + r16];
    float w3c0 = W3[r16],      w3c1 = W3[16 + r16];
    float w3c2 = W3[32 + r16], w3c3 = W3[48 + r16];
    float b3v = b3[0];

    for (int it = 0; it < 8; ++it) {
        int tile = wid * 8 + it;            // 65536 tiles of 16 edges
        int e = (tile << 4) + r16;
        int s = esrc[e];
        int t = edst[e];
        const float4* ps = (const float4*)(pre_s + (s << 6));
        const float4* pt = (const float4*)(pre_t + (t << 6));
        float4 s0 = ps[kg2], s1 = ps[kg2 + 1], s2 = ps[kg2 + 8], s3 = ps[kg2 + 9];
        float4 t0 = pt[kg2], t1 = pt[kg2 + 1], t2 = pt[kg2 + 8], t3 = pt[kg2 + 9];

        bf16x8 a0, a1;
        a0[0] = f2bf(fmaxf(s0.x + t0.x, 0.f));
        a0[1] = f2bf(fmaxf(s0.y + t0.y, 0.f));
        a0[2] = f2bf(fmaxf(s0.z + t0.z, 0.f));
        a0[3] = f2bf(fmaxf(s0.w + t0.w, 0.f));
        a0[4] = f2bf(fmaxf(s1.x + t1.x, 0.f));
        a0[5] = f2bf(fmaxf(s1.y + t1.y, 0.f));
        a0[6] = f2bf(fmaxf(s1.z + t1.z, 0.f));
        a0[7] = f2bf(fmaxf(s1.w + t1.w, 0.f));
        a1[0] = f2bf(fmaxf(s2.x + t2.x, 0.f));
        a1[1] = f2bf(fmaxf(s2.y + t2.y, 0.f));
        a1[2] = f2bf(fmaxf(s2.z + t2.z, 0.f));
        a1[3] = f2bf(fmaxf(s2.w + t2.w, 0.f));
        a1[4] = f2bf(fmaxf(s3.x + t3.x, 0.f));
        a1[5] = f2bf(fmaxf(s3.y + t3.y, 0.f));
        a1[6] = f2bf(fmaxf(s3.z + t3.z, 0.f));
        a1[7] = f2bf(fmaxf(s3.w + t3.w, 0.f));

        f32x4 acc0 = {0.f, 0.f, 0.f, 0.f};
        f32x4 acc1 = {0.f, 0.f, 0.f, 0.f};
        f32x4 acc2 = {0.f, 0.f, 0.f, 0.f};
        f32x4 acc3 = {0.f, 0.f, 0.f, 0.f};
        acc0 = __builtin_amdgcn_mfma_f32_16x16x32_bf16(a0, bw0, acc0, 0, 0, 0);
        acc0 = __builtin_amdgcn_mfma_f32_16x16x32_bf16(a1, bw1, acc0, 0, 0, 0);
        acc1 = __builtin_amdgcn_mfma_f32_16x16x32_bf16(a0, bw2, acc1, 0, 0, 0);
        acc1 = __builtin_amdgcn_mfma_f32_16x16x32_bf16(a1, bw3, acc1, 0, 0, 0);
        acc2 = __builtin_amdgcn_mfma_f32_16x16x32_bf16(a0, bw4, acc2, 0, 0, 0);
        acc2 = __builtin_amdgcn_mfma_f32_16x16x32_bf16(a1, bw5, acc2, 0, 0, 0);
        acc3 = __builtin_amdgcn_mfma_f32_16x16x32_bf16(a0, bw6, acc3, 0, 0, 0);
        acc3 = __builtin_amdgcn_mfma_f32_16x16x32_bf16(a1, bw7, acc3, 0, 0, 0);

        float p0 = fmaxf(acc0[0] + b2c0, 0.f) * w3c0 + fmaxf(acc1[0] + b2c1, 0.f) * w3c1
                 + fmaxf(acc2[0] + b2c2, 0.f) * w3c2 + fmaxf(acc3[0] + b2c3, 0.f) * w3c3;
        float p1 = fmaxf(acc0[1] + b2c0, 0.f) * w3c0 + fmaxf(acc1[1] + b2c1, 0.f) * w3c1
                 + fmaxf(acc2[1] + b2c2, 0.f) * w3c2 + fmaxf(acc3[1] + b2c3, 0.f) * w3c3;
        float p2 = fmaxf(acc0[2] + b2c0, 0.f) * w3c0 + fmaxf(acc1[2] + b2c1, 0.f) * w3c1
                 + fmaxf(acc2[2] + b2c2, 0.f) * w3c2 + fmaxf(acc3[2] + b2c3, 0.f) * w3c3;
        float p3 = fmaxf(acc0[3] + b2c0, 0.f) * w3c0 + fmaxf(acc1[3] + b2c1, 0.f) * w3c1
                 + fmaxf(acc2[3] + b2c2, 0.f) * w3c2 + fmaxf(acc3[3] + b2c3, 0.f) * w3c3;

        #pragma unroll
        for (int m = 1; m < 16; m <<= 1) {
            p0 += __shfl_xor(p0, m);
            p1 += __shfl_xor(p1, m);
            p2 += __shfl_xor(p2, m);
            p3 += __shfl_xor(p3, m);
        }
        if (r16 == 0) {
            float4 o;
            o.x = p0 + b3v; o.y = p1 + b3v; o.z = p2 + b3v; o.w = p3 + b3v;
            ((float4*)(logits + (tile << 4)))[kg] = o;   // rows kg*4..kg*4+3
        }
    }
}

// ---------------------------------------------------------------- per-graph softmax
__global__ __launch_bounds__(256) void k_softmax(const float* __restrict__ logits,
                                                 float* __restrict__ pi) {
    int g = blockIdx.x;
    const float* lg = logits + g * EE;
    __shared__ float wred[4];
    __shared__ float bval;
    int tid = threadIdx.x;
    int wid = tid >> 6, lane = tid & 63;

    float m = -1e30f;
    for (int i = tid; i < EE; i += 256) m = fmaxf(m, lg[i]);
    #pragma unroll
    for (int off = 32; off; off >>= 1) m = fmaxf(m, __shfl_xor(m, off));
    if (lane == 0) wred[wid] = m;
    __syncthreads();
    if (tid == 0) bval = fmaxf(fmaxf(wred[0], wred[1]), fmaxf(wred[2], wred[3]));
    __syncthreads();
    float gm = bval;

    float ssum = 0.f;
    for (int i = tid; i < EE; i += 256) ssum += expf(lg[i] - gm);
    #pragma unroll
    for (int off = 32; off; off >>= 1) ssum += __shfl_xor(ssum, off);
    if (lane == 0) wred[wid] = ssum;
    __syncthreads();
    if (tid == 0) bval = wred[0] + wred[1] + wred[2] + wred[3];
    __syncthreads();
    float inv = 1.f / bval;
    for (int i = tid; i < EE; i += 256) pi[g * EE + i] = expf(lg[i] - gm) * inv;
}

// ---------------------------------------------------------------- launch
extern "C" void kernel_launch(void* const* d_in, const int* in_sizes, int n_in,
                              void* d_out, int out_size, void* d_ws, size_t ws_size,
                              hipStream_t stream) {
    const float* x      = (const float*)d_in[0];
    const int*   ei     = (const int*)d_in[1];
    const float* ginW   = (const float*)d_in[3];   // [L,M,D,D]
    const float* ginb   = (const float*)d_in[4];   // [L,M,D]
    const float* ging   = (const float*)d_in[5];   // [L,M-1,D]
    const float* ginbe  = (const float*)d_in[6];   // [L,M-1,D]
    const float* aW1 = (const float*)d_in[7];
    const float* ab1 = (const float*)d_in[8];
    const float* aW2 = (const float*)d_in[9];
    const float* ab2 = (const float*)d_in[10];
    const float* aW3 = (const float*)d_in[11];
    const float* ab3 = (const float*)d_in[12];
    const float* cW1 = (const float*)d_in[13];
    const float* cb1 = (const float*)d_in[14];
    const float* cW2 = (const float*)d_in[15];
    const float* cb2 = (const float*)d_in[16];
    const float* cW3 = (const float*)d_in[17];
    const float* cb3 = (const float*)d_in[18];

    const int* esrc = ei;
    const int* edst = ei + TOTE;

    // workspace layout (floats):
    //   w0..w3 : 4 x 1M  feature temps (pre_t aliases w0+w1, logits aliases w3)
    //   nbr    : 2M ints @ +4M   (aliased by pre_s after GIN layers)
    //   small  : @ +6M   stats/gemb/gW/wfrag/cnt/off/cursor
    float* ws     = (float*)d_ws;
    float* w0     = ws;
    float* w1     = ws + 1 * 1048576;
    float* w2     = ws + 2 * 1048576;
    float* w3     = ws + 3 * 1048576;
    int*   nbr    = (int*)(ws + 4 * 1048576);   // 2M ints
    float* pre_s  = ws + 4 * 1048576;           // alias (used after nbr dead)
    float* small  = ws + 6 * 1048576;
    float* pre_t  = w0;                         // 2M floats (w0+w1)
    float* logits = w3;

    float* stats  = small;                      // 6 x 64
    float* gemb   = small + 512;                // 64 x 32
    float* gW     = small + 2560;               // 64 x 64
    short* wfrag  = (short*)(small + 6656);     // 8 x 64 x 8 bf16
    int*   cnt    = (int*)(small + 9216);       // 32768
    int*   off    = cnt + NTOT;                 // 32769
    int*   cursor = off + NTOT + 1;             // 32768

    float* out_pi = (float*)d_out;
    float* out_v  = out_pi + TOTE;

    #define GW(l, i)  (ginW  + ((l) * 3 + (i)) * DD * DD)
    #define GB(l, i)  (ginb  + ((l) * 3 + (i)) * DD)
    #define GG(l, i)  (ging  + ((l) * 2 + (i)) * DD)
    #define GBE(l, i) (ginbe + ((l) * 2 + (i)) * DD)
    #define ST(i)     (stats + (i) * 64)

    k_zero<<<1, 384, 0, stream>>>(stats);
    k_packW2<<<1, 64, 0, stream>>>(aW2, wfrag);

    // ---- CSR build (once; edge_index is layer-invariant)
    hipMemsetAsync(cnt, 0, NTOT * sizeof(int), stream);
    k_hist<<<TOTE / 256, 256, 0, stream>>>(esrc, edst, cnt);
    k_scan<<<BB, 512, 0, stream>>>(cnt, off, cursor);
    k_scatter<<<TOTE / 256, 256, 0, stream>>>(esrc, edst, cursor, nbr);

    // ---- layer 0 (input = x)
    k_aggc<<<NTOT / 32, 256, 0, stream>>>(x, off, nbr, w0);
    k_mm_stats<<<NTOT / 64, 256, 0, stream>>>(w0, GW(0, 0), GB(0, 0), w1, ST(0));
    k_bnmm<<<NTOT / 64, 256, 0, stream>>>(w1, ST(0), GG(0, 0), GBE(0, 0),
                                          GW(0, 1), GB(0, 1), w0, ST(1));
    k_bnmm<<<NTOT / 64, 256, 0, stream>>>(w0, ST(1), GG(0, 1), GBE(0, 1),
                                          GW(0, 2), GB(0, 2), w2, nullptr);

    // ---- layer 1 (feats = w2)
    k_aggc<<<NTOT / 32, 256, 0, stream>>>(w2, off, nbr, w0);
    k_mm_stats<<<NTOT / 64, 256, 0, stream>>>(w0, GW(1, 0), GB(1, 0), w1, ST(2));
    k_bnmm<<<NTOT / 64, 256, 0, stream>>>(w1, ST(2), GG(1, 0), GBE(1, 0),
                                          GW(1, 1), GB(1, 1), w0, ST(3));
    k_bnmm<<<NTOT / 64, 256, 0, stream>>>(w0, ST(3), GG(1, 1), GBE(1, 1),
                                          GW(1, 2), GB(1, 2), w3, nullptr);

    // ---- layer 2 (feats = w3)
    k_aggc<<<NTOT / 32, 256, 0, stream>>>(w3, off, nbr, w0);
    k_mm_stats<<<NTOT / 64, 256, 0, stream>>>(w0, GW(2, 0), GB(2, 0), w1, ST(4));
    k_bnmm<<<NTOT / 64, 256, 0, stream>>>(w1, ST(4), GG(2, 0), GBE(2, 0),
                                          GW(2, 1), GB(2, 1), w0, ST(5));
    k_bnmm<<<NTOT / 64, 256, 0, stream>>>(w0, ST(5), GG(2, 1), GBE(2, 1),
                                          GW(2, 2), GB(2, 2), w2, nullptr);
    // final feats in w2

    // ---- heads
    k_pool_critic<<<BB, 256, 0, stream>>>(w2, gemb, cW1, cb1, cW2, cb2, cW3, cb3, out_v);
    k_gembW<<<16, 256, 0, stream>>>(gemb, aW1, ab1, gW);
    k_pre<<<NTOT / 16, 256, 0, stream>>>(w2, aW1, gW, pre_s, pre_t);
    k_actor<<<2048, 256, 0, stream>>>(pre_s, pre_t, esrc, edst, wfrag,
                                      ab2, ab3, aW3, logits);
    k_softmax<<<BB, 256, 0, stream>>>(logits, out_pi);

    #undef GW
    #undef GB
    #undef GG
    #undef GBE
    #undef ST
}

// Round 6
// 557.202 us; speedup vs baseline: 4.0405x; 1.0500x over previous
//
#include <hip/hip_runtime.h>
#include <hip/hip_bf16.h>
#include <math.h>

// Problem constants (match reference)
#define BB    64          // graphs
#define NN    512         // nodes per graph
#define DD    32          // feature dim
#define EE    16384       // edges per graph
#define NTOT  32768       // B*N total nodes
#define TOTE  1048576     // B*E total edges
#define NDIR  2097152     // 2*TOTE edge-dirs
#define HA    64
#define HC    64
#define BN_EPS 1e-5f

typedef __attribute__((ext_vector_type(8))) short bf16x8;
typedef __attribute__((ext_vector_type(4))) float f32x4;

__device__ __forceinline__ short f2bf(float f) {
    union { __hip_bfloat16 h; short s; } u;
    u.h = __float2bfloat16(f);
    return u.s;
}

// ---------------------------------------------------------------- zero stats
__global__ void k_zero(float* __restrict__ stats) {
    if (threadIdx.x < 384) stats[threadIdx.x] = 0.f;
}

// ================================================================ CSR build
// (edge_index is layer-invariant: build once, reuse for all 3 aggregations)

__global__ __launch_bounds__(256) void k_hist(const int* __restrict__ esrc,
                                              const int* __restrict__ edst,
                                              int* __restrict__ cnt) {
    int e = blockIdx.x * 256 + threadIdx.x;
    int s = esrc[e];
    int t = edst[e];
    atomicAdd(&cnt[t], 1);
    atomicAdd(&cnt[s], 1);
}

// per-graph exclusive scan of 512 counts; global base = g*32768.
__global__ __launch_bounds__(512) void k_scan(const int* __restrict__ cnt,
                                              int* __restrict__ off,
                                              int* __restrict__ cursor) {
    __shared__ int buf0[512], buf1[512];
    int g = blockIdx.x, tid = threadIdx.x;
    int me = cnt[g * 512 + tid];
    buf0[tid] = me;
    __syncthreads();
    int* s = buf0; int* d = buf1;
    for (int dd = 1; dd < 512; dd <<= 1) {
        d[tid] = s[tid] + (tid >= dd ? s[tid - dd] : 0);
        __syncthreads();
        int* tmp = s; s = d; d = tmp;
    }
    int excl = s[tid] - me;
    int val = g * 32768 + excl;
    off[g * 512 + tid] = val;
    cursor[g * 512 + tid] = val;
    if (g == 0 && tid == 0) off[NTOT] = NDIR;
}

__global__ __launch_bounds__(256) void k_scatter(const int* __restrict__ esrc,
                                                 const int* __restrict__ edst,
                                                 int* __restrict__ cursor,
                                                 int* __restrict__ nbr) {
    int e = blockIdx.x * 256 + threadIdx.x;
    int s = esrc[e];
    int t = edst[e];
    nbr[atomicAdd(&cursor[t], 1)] = s;
    nbr[atomicAdd(&cursor[s], 1)] = t;
}

// ---------------------------------------------------------------- fused agg + first linear
// XCD-swizzled: graph g pinned to XCD g%8 so feats gathers stay L2-local.
// Phase 1: y[v] = feats[v] + sum_nbr feats[u] for 64 nodes -> LDS.
// Phase 2: H = Y@W + b from LDS, column stats for BN.
__global__ __launch_bounds__(256) void k_aggmm(const float* __restrict__ feats,
                                               const int* __restrict__ off,
                                               const int* __restrict__ nbr,
                                               const float* __restrict__ W,
                                               const float* __restrict__ bias,
                                               float* __restrict__ Hout,
                                               float* __restrict__ stats) {
    __shared__ float Ysh[64][32];    // 8 KB
    __shared__ float Wsh[DD * DD];   // 4 KB
    __shared__ float red[8][64];     // 2 KB
    int tid = threadIdx.x;
    // 512 blocks: b -> (xcd = b&7, idx = b>>3); g = xcd + 8*(idx>>3); unit = idx&7
    int b = blockIdx.x;
    int xcd = b & 7, idx = b >> 3;
    int g = xcd + ((idx >> 3) << 3);
    int unit = idx & 7;
    int rowbase = (g << 9) + (unit << 6);   // 64 nodes per block

    for (int i = tid; i < DD * DD; i += 256) Wsh[i] = W[i];

    // ---- phase 1: aggregation (8 lanes/node, 32 nodes/pass, 2 passes)
    int dl = tid & 7, ng = tid >> 3;
    const float4* f4 = (const float4*)feats;
    #pragma unroll
    for (int pass = 0; pass < 2; ++pass) {
        int v = rowbase + pass * 32 + ng;
        float4 acc = f4[v * 8 + dl];         // self term
        int j = off[v], e = off[v + 1];
        for (; j + 1 < e; j += 2) {
            int u0 = nbr[j], u1 = nbr[j + 1];
            float4 a = f4[u0 * 8 + dl];
            float4 c = f4[u1 * 8 + dl];
            acc.x += a.x + c.x; acc.y += a.y + c.y;
            acc.z += a.z + c.z; acc.w += a.w + c.w;
        }
        if (j < e) {
            float4 a = f4[nbr[j] * 8 + dl];
            acc.x += a.x; acc.y += a.y; acc.z += a.z; acc.w += a.w;
        }
        *(float4*)&Ysh[pass * 32 + ng][dl * 4] = acc;
    }
    __syncthreads();

    // ---- phase 2: H = Y@W + b (rows from LDS, broadcast reads)
    int c = tid & 31, rg = tid >> 5;
    float bcol = bias[c];
    float bsum = 0.f, bsq = 0.f;
    for (int rr = 0; rr < 8; ++rr) {
        int r = rg * 8 + rr;
        const float4* xr = (const float4*)Ysh[r];
        float accv = bcol;
        #pragma unroll
        for (int k4 = 0; k4 < 8; ++k4) {
            float4 xv = xr[k4];
            int kb = k4 * 4;
            accv = fmaf(xv.x, Wsh[(kb + 0) * DD + c], accv);
            accv = fmaf(xv.y, Wsh[(kb + 1) * DD + c], accv);
            accv = fmaf(xv.z, Wsh[(kb + 2) * DD + c], accv);
            accv = fmaf(xv.w, Wsh[(kb + 3) * DD + c], accv);
        }
        Hout[((rowbase + r) << 5) + c] = accv;
        bsum += accv; bsq += accv * accv;
    }
    red[rg][c] = bsum;
    red[rg][32 + c] = bsq;
    __syncthreads();
    if (tid < 64) {
        float v = 0.f;
        #pragma unroll
        for (int i = 0; i < 8; ++i) v += red[i][tid];
        atomicAdd(&stats[tid], v);
    }
}

// ---------------------------------------------------------------- relu(bn(Hin)) @ W + b
__global__ __launch_bounds__(256) void k_bnmm(const float* __restrict__ Hin,
                                              const float* __restrict__ instats,
                                              const float* __restrict__ gamma,
                                              const float* __restrict__ beta,
                                              const float* __restrict__ W,
                                              const float* __restrict__ bias,
                                              float* __restrict__ Hout,
                                              float* __restrict__ outstats) {
    __shared__ float Wsh[DD * DD];
    __shared__ float As[DD], Cs[DD];
    __shared__ float red[8][64];
    int tid = threadIdx.x;
    for (int i = tid; i < DD * DD; i += 256) Wsh[i] = W[i];
    if (tid < DD) {
        float s  = instats[tid];
        float q  = instats[DD + tid];
        float mu = s * (1.f / NTOT);
        float var = q * (1.f / NTOT) - mu * mu;
        float a  = gamma[tid] * rsqrtf(var + BN_EPS);
        As[tid]  = a;
        Cs[tid]  = beta[tid] - mu * a;
    }
    __syncthreads();

    int c = tid & 31, rg = tid >> 5;
    float bcol = bias[c];
    float bsum = 0.f, bsq = 0.f;
    for (int rr = 0; rr < 8; ++rr) {
        int row = blockIdx.x * 64 + rg * 8 + rr;
        const float4* xr = (const float4*)(Hin + (row << 5));
        float accv = bcol;
        #pragma unroll
        for (int k4 = 0; k4 < 8; ++k4) {
            float4 xv = xr[k4];
            int kb = k4 * 4;
            float xn;
            xn = fmaxf(fmaf(xv.x, As[kb + 0], Cs[kb + 0]), 0.f);
            accv = fmaf(xn, Wsh[(kb + 0) * DD + c], accv);
            xn = fmaxf(fmaf(xv.y, As[kb + 1], Cs[kb + 1]), 0.f);
            accv = fmaf(xn, Wsh[(kb + 1) * DD + c], accv);
            xn = fmaxf(fmaf(xv.z, As[kb + 2], Cs[kb + 2]), 0.f);
            accv = fmaf(xn, Wsh[(kb + 2) * DD + c], accv);
            xn = fmaxf(fmaf(xv.w, As[kb + 3], Cs[kb + 3]), 0.f);
            accv = fmaf(xn, Wsh[(kb + 3) * DD + c], accv);
        }
        Hout[(row << 5) + c] = accv;
        bsum += accv; bsq += accv * accv;
    }
    if (outstats) {
        red[rg][c] = bsum;
        red[rg][32 + c] = bsq;
        __syncthreads();
        if (tid < 64) {
            float v = 0.f;
            #pragma unroll
            for (int i = 0; i < 8; ++i) v += red[i][tid];
            atomicAdd(&outstats[tid], v);
        }
    }
}

// ---------------------------------------------------------------- pool + critic
__global__ __launch_bounds__(256) void k_pool_critic(const float* __restrict__ feats,
                                                     float* __restrict__ gemb,
                                                     const float* __restrict__ W1,
                                                     const float* __restrict__ b1,
                                                     const float* __restrict__ W2,
                                                     const float* __restrict__ b2,
                                                     const float* __restrict__ W3,
                                                     const float* __restrict__ b3,
                                                     float* __restrict__ value) {
    int g = blockIdx.x;
    __shared__ float red[8][DD];
    __shared__ float ge[DD];
    __shared__ float h1[HC];
    __shared__ float h2[HC];
    int tid = threadIdx.x;
    int d = tid & 31, grp = tid >> 5;
    float s = 0.f;
    const float* fg = feats + g * NN * DD;
    for (int n = grp; n < NN; n += 8) s += fg[n * DD + d];
    red[grp][d] = s;
    __syncthreads();
    if (tid < DD) {
        float t = 0.f;
        #pragma unroll
        for (int i = 0; i < 8; ++i) t += red[i][tid];
        t *= (1.f / NN);
        ge[tid] = t;
        gemb[g * DD + tid] = t;
    }
    __syncthreads();
    if (tid < HC) {
        float a = b1[tid];
        for (int k = 0; k < DD; ++k) a = fmaf(ge[k], W1[k * HC + tid], a);
        h1[tid] = fmaxf(a, 0.f);
    }
    __syncthreads();
    if (tid < HC) {
        float a = b2[tid];
        for (int k = 0; k < HC; ++k) a = fmaf(h1[k], W2[k * HC + tid], a);
        h2[tid] = fmaxf(a, 0.f);
    }
    __syncthreads();
    if (tid < 64) {
        float p = h2[tid] * W3[tid];
        #pragma unroll
        for (int off = 32; off; off >>= 1) p += __shfl_xor(p, off);
        if (tid == 0) value[g] = p + b3[0];
    }
}

// ---------------------------------------------------------------- gW[g][c] = b1[c] + gemb[g]@W1a
__global__ void k_gembW(const float* __restrict__ gemb,
                        const float* __restrict__ W1,
                        const float* __restrict__ b1,
                        float* __restrict__ gW) {
    int idx = blockIdx.x * 256 + threadIdx.x;   // 4096 = 64 graphs x 64 cols
    int g = idx >> 6, c = idx & 63;
    float a = b1[c];
    #pragma unroll 4
    for (int k = 0; k < DD; ++k) a = fmaf(gemb[(g << 5) + k], W1[k * HA + c], a);
    gW[idx] = a;
}

// ---------------------------------------------------------------- per-node actor precompute
// pre_s[n] = feats[n]@W1b + gW[g(n)]  (gW includes b1);  pre_t[n] = feats[n]@W1c
__global__ __launch_bounds__(256) void k_pre(const float* __restrict__ feats,
                                             const float* __restrict__ W1,
                                             const float* __restrict__ gW,
                                             float* __restrict__ pre_s,
                                             float* __restrict__ pre_t) {
    __shared__ float Wb[DD * HA];   // 8 KB
    __shared__ float Wc[DD * HA];   // 8 KB
    int tid = threadIdx.x;
    for (int i = tid; i < DD * HA; i += 256) {
        Wb[i] = W1[DD * HA + i];       // rows 32..63 of W1
        Wc[i] = W1[2 * DD * HA + i];   // rows 64..95
    }
    __syncthreads();
    int c = tid & 63, rl = tid >> 6;
    for (int rr = 0; rr < 4; ++rr) {
        int row = blockIdx.x * 16 + rr * 4 + rl;
        const float4* fr = (const float4*)(feats + (row << 5));
        float as = gW[((row >> 9) << 6) + c];
        float at = 0.f;
        #pragma unroll
        for (int k4 = 0; k4 < 8; ++k4) {
            float4 f = fr[k4];
            int kb = k4 * 4;
            as = fmaf(f.x, Wb[(kb + 0) * HA + c], as); at = fmaf(f.x, Wc[(kb + 0) * HA + c], at);
            as = fmaf(f.y, Wb[(kb + 1) * HA + c], as); at = fmaf(f.y, Wc[(kb + 1) * HA + c], at);
            as = fmaf(f.z, Wb[(kb + 2) * HA + c], as); at = fmaf(f.z, Wc[(kb + 2) * HA + c], at);
            as = fmaf(f.w, Wb[(kb + 3) * HA + c], as); at = fmaf(f.w, Wc[(kb + 3) * HA + c], at);
        }
        pre_s[(row << 6) + c] = as;
        pre_t[(row << 6) + c] = at;
    }
}

// ---------------------------------------------------------------- pack W2 into MFMA B-fragments
__global__ void k_packW2(const float* __restrict__ W2, short* __restrict__ wfrag) {
    int lane = threadIdx.x;
    if (lane < 64) {
        #pragma unroll
        for (int f = 0; f < 8; ++f) {
            int nt = f >> 1, kh = f & 1;
            int n = nt * 16 + (lane & 15);
            int kbase = kh * 32 + (lane >> 4) * 8;
            #pragma unroll
            for (int j = 0; j < 8; ++j)
                wfrag[(f * 64 + lane) * 8 + j] = f2bf(W2[(kbase + j) * HA + n]);
        }
    }
}

// ---------------------------------------------------------------- actor: MFMA over edges
// XCD-swizzled: graph g's 32 blocks pinned to XCD g%8 -> pre_s/pre_t stay in
// that XCD's L2 (2 MB working set per XCD vs 4 MB L2). Kills the 8x HBM
// duplication seen in round 3 (FETCH 131 MB -> ~25 MB).
__global__ __launch_bounds__(256) void k_actor(const float* __restrict__ pre_s,
                                               const float* __restrict__ pre_t,
                                               const int* __restrict__ esrc,
                                               const int* __restrict__ edst,
                                               const short* __restrict__ wfrag,
                                               const float* __restrict__ b2,
                                               const float* __restrict__ b3,
                                               const float* __restrict__ W3,
                                               float* __restrict__ logits) {
    int lane = threadIdx.x & 63;
    int wv   = threadIdx.x >> 6;
    int b    = blockIdx.x;                 // 0..2047
    int xcd  = b & 7;
    int idx  = b >> 3;                     // 0..255
    int g    = xcd + ((idx >> 5) << 3);    // graph, g%8 == xcd
    int unit = idx & 31;                   // 32 blocks per graph
    int r16  = lane & 15;
    int kg   = lane >> 4;          // k-group 0..3
    int kg2  = kg * 2;

    const bf16x8* wf = (const bf16x8*)wfrag;
    bf16x8 bw0 = wf[0 * 64 + lane];
    bf16x8 bw1 = wf[1 * 64 + lane];
    bf16x8 bw2 = wf[2 * 64 + lane];
    bf16x8 bw3 = wf[3 * 64 + lane];
    bf16x8 bw4 = wf[4 * 64 + lane];
    bf16x8 bw5 = wf[5 * 64 + lane];
    bf16x8 bw6 = wf[6 * 64 + lane];
    bf16x8 bw7 = wf[7 * 64 + lane];

    float b2c0 = b2[r16],      b2c1 = b2[16 + r16];
    float b2c2 = b2[32 + r16], b2c3 = b2[48 + r16];
    float w3c0 = W3[r16],      w3c1 = W3[16 + r16];
    float w3c2 = W3[32 + r16], w3c3 = W3[48 + r16];
    float b3v = b3[0];

    for (int it = 0; it < 8; ++it) {
        int tile = (g << 10) + (unit << 5) + (wv << 3) + it;
        int e = (tile << 4) + r16;
        int s = esrc[e];
        int t = edst[e];
        const float4* ps = (const float4*)(pre_s + (s << 6));
        const float4* pt = (const float4*)(pre_t + (t << 6));
        float4 s0 = ps[kg2], s1 = ps[kg2 + 1], s2 = ps[kg2 + 8], s3 = ps[kg2 + 9];
        float4 t0 = pt[kg2], t1 = pt[kg2 + 1], t2 = pt[kg2 + 8], t3 = pt[kg2 + 9];

        bf16x8 a0, a1;
        a0[0] = f2bf(fmaxf(s0.x + t0.x, 0.f));
        a0[1] = f2bf(fmaxf(s0.y + t0.y, 0.f));
        a0[2] = f2bf(fmaxf(s0.z + t0.z, 0.f));
        a0[3] = f2bf(fmaxf(s0.w + t0.w, 0.f));
        a0[4] = f2bf(fmaxf(s1.x + t1.x, 0.f));
        a0[5] = f2bf(fmaxf(s1.y + t1.y, 0.f));
        a0[6] = f2bf(fmaxf(s1.z + t1.z, 0.f));
        a0[7] = f2bf(fmaxf(s1.w + t1.w, 0.f));
        a1[0] = f2bf(fmaxf(s2.x + t2.x, 0.f));
        a1[1] = f2bf(fmaxf(s2.y + t2.y, 0.f));
        a1[2] = f2bf(fmaxf(s2.z + t2.z, 0.f));
        a1[3] = f2bf(fmaxf(s2.w + t2.w, 0.f));
        a1[4] = f2bf(fmaxf(s3.x + t3.x, 0.f));
        a1[5] = f2bf(fmaxf(s3.y + t3.y, 0.f));
        a1[6] = f2bf(fmaxf(s3.z + t3.z, 0.f));
        a1[7] = f2bf(fmaxf(s3.w + t3.w, 0.f));

        f32x4 acc0 = {0.f, 0.f, 0.f, 0.f};
        f32x4 acc1 = {0.f, 0.f, 0.f, 0.f};
        f32x4 acc2 = {0.f, 0.f, 0.f, 0.f};
        f32x4 acc3 = {0.f, 0.f, 0.f, 0.f};
        acc0 = __builtin_amdgcn_mfma_f32_16x16x32_bf16(a0, bw0, acc0, 0, 0, 0);
        acc0 = __builtin_amdgcn_mfma_f32_16x16x32_bf16(a1, bw1, acc0, 0, 0, 0);
        acc1 = __builtin_amdgcn_mfma_f32_16x16x32_bf16(a0, bw2, acc1, 0, 0, 0);
        acc1 = __builtin_amdgcn_mfma_f32_16x16x32_bf16(a1, bw3, acc1, 0, 0, 0);
        acc2 = __builtin_amdgcn_mfma_f32_16x16x32_bf16(a0, bw4, acc2, 0, 0, 0);
        acc2 = __builtin_amdgcn_mfma_f32_16x16x32_bf16(a1, bw5, acc2, 0, 0, 0);
        acc3 = __builtin_amdgcn_mfma_f32_16x16x32_bf16(a0, bw6, acc3, 0, 0, 0);
        acc3 = __builtin_amdgcn_mfma_f32_16x16x32_bf16(a1, bw7, acc3, 0, 0, 0);

        float p0 = fmaxf(acc0[0] + b2c0, 0.f) * w3c0 + fmaxf(acc1[0] + b2c1, 0.f) * w3c1
                 + fmaxf(acc2[0] + b2c2, 0.f) * w3c2 + fmaxf(acc3[0] + b2c3, 0.f) * w3c3;
        float p1 = fmaxf(acc0[1] + b2c0, 0.f) * w3c0 + fmaxf(acc1[1] + b2c1, 0.f) * w3c1
                 + fmaxf(acc2[1] + b2c2, 0.f) * w3c2 + fmaxf(acc3[1] + b2c3, 0.f) * w3c3;
        float p2 = fmaxf(acc0[2] + b2c0, 0.f) * w3c0 + fmaxf(acc1[2] + b2c1, 0.f) * w3c1
                 + fmaxf(acc2[2] + b2c2, 0.f) * w3c2 + fmaxf(acc3[2] + b2c3, 0.f) * w3c3;
        float p3 = fmaxf(acc0[3] + b2c0, 0.f) * w3c0 + fmaxf(acc1[3] + b2c1, 0.f) * w3c1
                 + fmaxf(acc2[3] + b2c2, 0.f) * w3c2 + fmaxf(acc3[3] + b2c3, 0.f) * w3c3;

        #pragma unroll
        for (int m = 1; m < 16; m <<= 1) {
            p0 += __shfl_xor(p0, m);
            p1 += __shfl_xor(p1, m);
            p2 += __shfl_xor(p2, m);
            p3 += __shfl_xor(p3, m);
        }
        if (r16 == 0) {
            float4 o;
            o.x = p0 + b3v; o.y = p1 + b3v; o.z = p2 + b3v; o.w = p3 + b3v;
            ((float4*)(logits + (tile << 4)))[kg] = o;   // rows kg*4..kg*4+3
        }
    }
}

// ---------------------------------------------------------------- per-graph softmax
__global__ __launch_bounds__(256) void k_softmax(const float* __restrict__ logits,
                                                 float* __restrict__ pi) {
    int g = blockIdx.x;
    const float* lg = logits + g * EE;
    __shared__ float wred[4];
    __shared__ float bval;
    int tid = threadIdx.x;
    int wid = tid >> 6, lane = tid & 63;

    float m = -1e30f;
    for (int i = tid; i < EE; i += 256) m = fmaxf(m, lg[i]);
    #pragma unroll
    for (int off = 32; off; off >>= 1) m = fmaxf(m, __shfl_xor(m, off));
    if (lane == 0) wred[wid] = m;
    __syncthreads();
    if (tid == 0) bval = fmaxf(fmaxf(wred[0], wred[1]), fmaxf(wred[2], wred[3]));
    __syncthreads();
    float gm = bval;

    float ssum = 0.f;
    for (int i = tid; i < EE; i += 256) ssum += expf(lg[i] - gm);
    #pragma unroll
    for (int off = 32; off; off >>= 1) ssum += __shfl_xor(ssum, off);
    if (lane == 0) wred[wid] = ssum;
    __syncthreads();
    if (tid == 0) bval = wred[0] + wred[1] + wred[2] + wred[3];
    __syncthreads();
    float inv = 1.f / bval;
    for (int i = tid; i < EE; i += 256) pi[g * EE + i] = expf(lg[i] - gm) * inv;
}

// ---------------------------------------------------------------- launch
extern "C" void kernel_launch(void* const* d_in, const int* in_sizes, int n_in,
                              void* d_out, int out_size, void* d_ws, size_t ws_size,
                              hipStream_t stream) {
    const float* x      = (const float*)d_in[0];
    const int*   ei     = (const int*)d_in[1];
    const float* ginW   = (const float*)d_in[3];   // [L,M,D,D]
    const float* ginb   = (const float*)d_in[4];   // [L,M,D]
    const float* ging   = (const float*)d_in[5];   // [L,M-1,D]
    const float* ginbe  = (const float*)d_in[6];   // [L,M-1,D]
    const float* aW1 = (const float*)d_in[7];
    const float* ab1 = (const float*)d_in[8];
    const float* aW2 = (const float*)d_in[9];
    const float* ab2 = (const float*)d_in[10];
    const float* aW3 = (const float*)d_in[11];
    const float* ab3 = (const float*)d_in[12];
    const float* cW1 = (const float*)d_in[13];
    const float* cb1 = (const float*)d_in[14];
    const float* cW2 = (const float*)d_in[15];
    const float* cb2 = (const float*)d_in[16];
    const float* cW3 = (const float*)d_in[17];
    const float* cb3 = (const float*)d_in[18];

    const int* esrc = ei;
    const int* edst = ei + TOTE;

    // workspace layout (floats):
    //   w0..w3 : 4 x 1M  feature temps (pre_t aliases w0+w1, logits aliases w3)
    //   nbr    : 2M ints @ +4M   (aliased by pre_s after GIN layers)
    //   small  : @ +6M   stats/gemb/gW/wfrag/cnt/off/cursor
    float* ws     = (float*)d_ws;
    float* w0     = ws;
    float* w1     = ws + 1 * 1048576;
    float* w2     = ws + 2 * 1048576;
    float* w3     = ws + 3 * 1048576;
    int*   nbr    = (int*)(ws + 4 * 1048576);   // 2M ints
    float* pre_s  = ws + 4 * 1048576;           // alias (used after nbr dead)
    float* small  = ws + 6 * 1048576;
    float* pre_t  = w0;                         // 2M floats (w0+w1)
    float* logits = w3;

    float* stats  = small;                      // 6 x 64
    float* gemb   = small + 512;                // 64 x 32
    float* gW     = small + 2560;               // 64 x 64
    short* wfrag  = (short*)(small + 6656);     // 8 x 64 x 8 bf16
    int*   cnt    = (int*)(small + 9216);       // 32768
    int*   off    = cnt + NTOT;                 // 32769
    int*   cursor = off + NTOT + 1;             // 32768

    float* out_pi = (float*)d_out;
    float* out_v  = out_pi + TOTE;

    #define GW(l, i)  (ginW  + ((l) * 3 + (i)) * DD * DD)
    #define GB(l, i)  (ginb  + ((l) * 3 + (i)) * DD)
    #define GG(l, i)  (ging  + ((l) * 2 + (i)) * DD)
    #define GBE(l, i) (ginbe + ((l) * 2 + (i)) * DD)
    #define ST(i)     (stats + (i) * 64)

    k_zero<<<1, 384, 0, stream>>>(stats);
    k_packW2<<<1, 64, 0, stream>>>(aW2, wfrag);

    // ---- CSR build (once; edge_index is layer-invariant)
    hipMemsetAsync(cnt, 0, NTOT * sizeof(int), stream);
    k_hist<<<TOTE / 256, 256, 0, stream>>>(esrc, edst, cnt);
    k_scan<<<BB, 512, 0, stream>>>(cnt, off, cursor);
    k_scatter<<<TOTE / 256, 256, 0, stream>>>(esrc, edst, cursor, nbr);

    // ---- layer 0 (input = x)
    k_aggmm<<<NTOT / 64, 256, 0, stream>>>(x, off, nbr, GW(0, 0), GB(0, 0), w1, ST(0));
    k_bnmm<<<NTOT / 64, 256, 0, stream>>>(w1, ST(0), GG(0, 0), GBE(0, 0),
                                          GW(0, 1), GB(0, 1), w0, ST(1));
    k_bnmm<<<NTOT / 64, 256, 0, stream>>>(w0, ST(1), GG(0, 1), GBE(0, 1),
                                          GW(0, 2), GB(0, 2), w2, nullptr);

    // ---- layer 1 (feats = w2)
    k_aggmm<<<NTOT / 64, 256, 0, stream>>>(w2, off, nbr, GW(1, 0), GB(1, 0), w1, ST(2));
    k_bnmm<<<NTOT / 64, 256, 0, stream>>>(w1, ST(2), GG(1, 0), GBE(1, 0),
                                          GW(1, 1), GB(1, 1), w0, ST(3));
    k_bnmm<<<NTOT / 64, 256, 0, stream>>>(w0, ST(3), GG(1, 1), GBE(1, 1),
                                          GW(1, 2), GB(1, 2), w3, nullptr);

    // ---- layer 2 (feats = w3)
    k_aggmm<<<NTOT / 64, 256, 0, stream>>>(w3, off, nbr, GW(2, 0), GB(2, 0), w1, ST(4));
    k_bnmm<<<NTOT / 64, 256, 0, stream>>>(w1, ST(4), GG(2, 0), GBE(2, 0),
                                          GW(2, 1), GB(2, 1), w0, ST(5));
    k_bnmm<<<NTOT / 64, 256, 0, stream>>>(w0, ST(5), GG(2, 1), GBE(2, 1),
                                          GW(2, 2), GB(2, 2), w2, nullptr);
    // final feats in w2

    // ---- heads
    k_pool_critic<<<BB, 256, 0, stream>>>(w2, gemb, cW1, cb1, cW2, cb2, cW3, cb3, out_v);
    k_gembW<<<16, 256, 0, stream>>>(gemb, aW1, ab1, gW);
    k_pre<<<NTOT / 16, 256, 0, stream>>>(w2, aW1, gW, pre_s, pre_t);
    k_actor<<<2048, 256, 0, stream>>>(pre_s, pre_t, esrc, edst, wfrag,
                                      ab2, ab3, aW3, logits);
    k_softmax<<<BB, 256, 0, stream>>>(logits, out_pi);

    #undef GW
    #undef GB
    #undef GG
    #undef GBE
    #undef ST
}

// Round 9
// 551.944 us; speedup vs baseline: 4.0790x; 1.0095x over previous
//
#include <hip/hip_runtime.h>
#include <hip/hip_bf16.h>
#include <math.h>

// Problem constants (match reference)
#define BB    64          // graphs
#define NN    512         // nodes per graph
#define DD    32          // feature dim
#define EE    16384       // edges per graph
#define NTOT  32768       // B*N total nodes
#define TOTE  1048576     // B*E total edges
#define NDIR  2097152     // 2*TOTE edge-dirs
#define HA    64
#define HC    64
#define BN_EPS 1e-5f

typedef __attribute__((ext_vector_type(8))) short bf16x8;
typedef __attribute__((ext_vector_type(4))) float f32x4;

__device__ __forceinline__ short f2bf(float f) {
    union { __hip_bfloat16 h; short s; } u;
    u.h = __float2bfloat16(f);
    return u.s;
}

// ---------------------------------------------------------------- zero stats
__global__ void k_zero(float* __restrict__ stats) {
    if (threadIdx.x < 384) stats[threadIdx.x] = 0.f;
}

// ================================================================ CSR build
// (edge_index is layer-invariant: build once, reuse for all 3 aggregations)

__global__ __launch_bounds__(256) void k_hist(const int* __restrict__ esrc,
                                              const int* __restrict__ edst,
                                              int* __restrict__ cnt) {
    int e = blockIdx.x * 256 + threadIdx.x;
    int s = esrc[e];
    int t = edst[e];
    atomicAdd(&cnt[t], 1);
    atomicAdd(&cnt[s], 1);
}

// per-graph exclusive scan of 512 counts; global base = g*32768.
__global__ __launch_bounds__(512) void k_scan(const int* __restrict__ cnt,
                                              int* __restrict__ off,
                                              int* __restrict__ cursor) {
    __shared__ int buf0[512], buf1[512];
    int g = blockIdx.x, tid = threadIdx.x;
    int me = cnt[g * 512 + tid];
    buf0[tid] = me;
    __syncthreads();
    int* s = buf0; int* d = buf1;
    for (int dd = 1; dd < 512; dd <<= 1) {
        d[tid] = s[tid] + (tid >= dd ? s[tid - dd] : 0);
        __syncthreads();
        int* tmp = s; s = d; d = tmp;
    }
    int excl = s[tid] - me;
    int val = g * 32768 + excl;
    off[g * 512 + tid] = val;
    cursor[g * 512 + tid] = val;
    if (g == 0 && tid == 0) off[NTOT] = NDIR;
}

__global__ __launch_bounds__(256) void k_scatter(const int* __restrict__ esrc,
                                                 const int* __restrict__ edst,
                                                 int* __restrict__ cursor,
                                                 int* __restrict__ nbr) {
    int e = blockIdx.x * 256 + threadIdx.x;
    int s = esrc[e];
    int t = edst[e];
    nbr[atomicAdd(&cursor[t], 1)] = s;
    nbr[atomicAdd(&cursor[s], 1)] = t;
}

// ---------------------------------------------------------------- fused agg + first linear
// XCD-swizzled: graph g pinned to XCD g%8 so feats gathers stay L2-local.
__global__ __launch_bounds__(256) void k_aggmm(const float* __restrict__ feats,
                                               const int* __restrict__ off,
                                               const int* __restrict__ nbr,
                                               const float* __restrict__ W,
                                               const float* __restrict__ bias,
                                               float* __restrict__ Hout,
                                               float* __restrict__ stats) {
    __shared__ float Ysh[64][32];    // 8 KB
    __shared__ float Wsh[DD * DD];   // 4 KB
    __shared__ float red[8][64];     // 2 KB
    int tid = threadIdx.x;
    int b = blockIdx.x;
    int xcd = b & 7, idx = b >> 3;
    int g = xcd + ((idx >> 3) << 3);
    int unit = idx & 7;
    int rowbase = (g << 9) + (unit << 6);   // 64 nodes per block

    for (int i = tid; i < DD * DD; i += 256) Wsh[i] = W[i];

    // ---- phase 1: aggregation (8 lanes/node, 32 nodes/pass, 2 passes)
    int dl = tid & 7, ng = tid >> 3;
    const float4* f4 = (const float4*)feats;
    #pragma unroll
    for (int pass = 0; pass < 2; ++pass) {
        int v = rowbase + pass * 32 + ng;
        float4 acc = f4[v * 8 + dl];         // self term
        int j = off[v], e = off[v + 1];
        for (; j + 1 < e; j += 2) {
            int u0 = nbr[j], u1 = nbr[j + 1];
            float4 a = f4[u0 * 8 + dl];
            float4 c = f4[u1 * 8 + dl];
            acc.x += a.x + c.x; acc.y += a.y + c.y;
            acc.z += a.z + c.z; acc.w += a.w + c.w;
        }
        if (j < e) {
            float4 a = f4[nbr[j] * 8 + dl];
            acc.x += a.x; acc.y += a.y; acc.z += a.z; acc.w += a.w;
        }
        *(float4*)&Ysh[pass * 32 + ng][dl * 4] = acc;
    }
    __syncthreads();

    // ---- phase 2: H = Y@W + b (rows from LDS, broadcast reads)
    int c = tid & 31, rg = tid >> 5;
    float bcol = bias[c];
    float bsum = 0.f, bsq = 0.f;
    for (int rr = 0; rr < 8; ++rr) {
        int r = rg * 8 + rr;
        const float4* xr = (const float4*)Ysh[r];
        float accv = bcol;
        #pragma unroll
        for (int k4 = 0; k4 < 8; ++k4) {
            float4 xv = xr[k4];
            int kb = k4 * 4;
            accv = fmaf(xv.x, Wsh[(kb + 0) * DD + c], accv);
            accv = fmaf(xv.y, Wsh[(kb + 1) * DD + c], accv);
            accv = fmaf(xv.z, Wsh[(kb + 2) * DD + c], accv);
            accv = fmaf(xv.w, Wsh[(kb + 3) * DD + c], accv);
        }
        Hout[((rowbase + r) << 5) + c] = accv;
        bsum += accv; bsq += accv * accv;
    }
    red[rg][c] = bsum;
    red[rg][32 + c] = bsq;
    __syncthreads();
    if (tid < 64) {
        float v = 0.f;
        #pragma unroll
        for (int i = 0; i < 8; ++i) v += red[i][tid];
        atomicAdd(&stats[tid], v);
    }
}

// ---------------------------------------------------------------- relu(bn(Hin)) @ W + b
// XCD-swizzled rows (same graph->XCD pinning as k_aggmm) so Hin stays L2-local.
__global__ __launch_bounds__(256) void k_bnmm(const float* __restrict__ Hin,
                                              const float* __restrict__ instats,
                                              const float* __restrict__ gamma,
                                              const float* __restrict__ beta,
                                              const float* __restrict__ W,
                                              const float* __restrict__ bias,
                                              float* __restrict__ Hout,
                                              float* __restrict__ outstats) {
    __shared__ float Wsh[DD * DD];
    __shared__ float As[DD], Cs[DD];
    __shared__ float red[8][64];
    int tid = threadIdx.x;
    int b = blockIdx.x;
    int xcd = b & 7, idx = b >> 3;
    int g = xcd + ((idx >> 3) << 3);
    int unit = idx & 7;
    int rowbase = (g << 9) + (unit << 6);

    for (int i = tid; i < DD * DD; i += 256) Wsh[i] = W[i];
    if (tid < DD) {
        float s  = instats[tid];
        float q  = instats[DD + tid];
        float mu = s * (1.f / NTOT);
        float var = q * (1.f / NTOT) - mu * mu;
        float a  = gamma[tid] * rsqrtf(var + BN_EPS);
        As[tid]  = a;
        Cs[tid]  = beta[tid] - mu * a;
    }
    __syncthreads();

    int c = tid & 31, rg = tid >> 5;
    float bcol = bias[c];
    float bsum = 0.f, bsq = 0.f;
    for (int rr = 0; rr < 8; ++rr) {
        int row = rowbase + rg * 8 + rr;
        const float4* xr = (const float4*)(Hin + (row << 5));
        float accv = bcol;
        #pragma unroll
        for (int k4 = 0; k4 < 8; ++k4) {
            float4 xv = xr[k4];
            int kb = k4 * 4;
            float xn;
            xn = fmaxf(fmaf(xv.x, As[kb + 0], Cs[kb + 0]), 0.f);
            accv = fmaf(xn, Wsh[(kb + 0) * DD + c], accv);
            xn = fmaxf(fmaf(xv.y, As[kb + 1], Cs[kb + 1]), 0.f);
            accv = fmaf(xn, Wsh[(kb + 1) * DD + c], accv);
            xn = fmaxf(fmaf(xv.z, As[kb + 2], Cs[kb + 2]), 0.f);
            accv = fmaf(xn, Wsh[(kb + 2) * DD + c], accv);
            xn = fmaxf(fmaf(xv.w, As[kb + 3], Cs[kb + 3]), 0.f);
            accv = fmaf(xn, Wsh[(kb + 3) * DD + c], accv);
        }
        Hout[(row << 5) + c] = accv;
        bsum += accv; bsq += accv * accv;
    }
    if (outstats) {
        red[rg][c] = bsum;
        red[rg][32 + c] = bsq;
        __syncthreads();
        if (tid < 64) {
            float v = 0.f;
            #pragma unroll
            for (int i = 0; i < 8; ++i) v += red[i][tid];
            atomicAdd(&outstats[tid], v);
        }
    }
}

// ---------------------------------------------------------------- pool + critic
// 64 blocks: block b -> graph b; b%8 == g%8 already matches XCD pinning.
__global__ __launch_bounds__(256) void k_pool_critic(const float* __restrict__ feats,
                                                     float* __restrict__ gemb,
                                                     const float* __restrict__ W1,
                                                     const float* __restrict__ b1,
                                                     const float* __restrict__ W2,
                                                     const float* __restrict__ b2,
                                                     const float* __restrict__ W3,
                                                     const float* __restrict__ b3,
                                                     float* __restrict__ value) {
    int g = blockIdx.x;
    __shared__ float red[8][DD];
    __shared__ float ge[DD];
    __shared__ float h1[HC];
    __shared__ float h2[HC];
    int tid = threadIdx.x;
    int d = tid & 31, grp = tid >> 5;
    float s = 0.f;
    const float* fg = feats + g * NN * DD;
    for (int n = grp; n < NN; n += 8) s += fg[n * DD + d];
    red[grp][d] = s;
    __syncthreads();
    if (tid < DD) {
        float t = 0.f;
        #pragma unroll
        for (int i = 0; i < 8; ++i) t += red[i][tid];
        t *= (1.f / NN);
        ge[tid] = t;
        gemb[g * DD + tid] = t;
    }
    __syncthreads();
    if (tid < HC) {
        float a = b1[tid];
        for (int k = 0; k < DD; ++k) a = fmaf(ge[k], W1[k * HC + tid], a);
        h1[tid] = fmaxf(a, 0.f);
    }
    __syncthreads();
    if (tid < HC) {
        float a = b2[tid];
        for (int k = 0; k < HC; ++k) a = fmaf(h1[k], W2[k * HC + tid], a);
        h2[tid] = fmaxf(a, 0.f);
    }
    __syncthreads();
    if (tid < 64) {
        float p = h2[tid] * W3[tid];
        #pragma unroll
        for (int off = 32; off; off >>= 1) p += __shfl_xor(p, off);
        if (tid == 0) value[g] = p + b3[0];
    }
}

// ---------------------------------------------------------------- gW[g][c] = b1[c] + gemb[g]@W1a
__global__ void k_gembW(const float* __restrict__ gemb,
                        const float* __restrict__ W1,
                        const float* __restrict__ b1,
                        float* __restrict__ gW) {
    int idx = blockIdx.x * 256 + threadIdx.x;   // 4096 = 64 graphs x 64 cols
    int g = idx >> 6, c = idx & 63;
    float a = b1[c];
    #pragma unroll 4
    for (int k = 0; k < DD; ++k) a = fmaf(gemb[(g << 5) + k], W1[k * HA + c], a);
    gW[idx] = a;
}

// ---------------------------------------------------------------- per-node actor precompute
// XCD-swizzled: graph g's 32 blocks pinned to XCD g%8 (matches feats producer
// and actor consumer).
__global__ __launch_bounds__(256) void k_pre(const float* __restrict__ feats,
                                             const float* __restrict__ W1,
                                             const float* __restrict__ gW,
                                             float* __restrict__ pre_s,
                                             float* __restrict__ pre_t) {
    __shared__ float Wb[DD * HA];   // 8 KB
    __shared__ float Wc[DD * HA];   // 8 KB
    int tid = threadIdx.x;
    for (int i = tid; i < DD * HA; i += 256) {
        Wb[i] = W1[DD * HA + i];       // rows 32..63 of W1
        Wc[i] = W1[2 * DD * HA + i];   // rows 64..95
    }
    __syncthreads();
    int b = blockIdx.x;                    // 2048 blocks
    int xcd = b & 7, idx = b >> 3;         // idx 0..255
    int g = xcd + ((idx >> 5) << 3);       // graph, g%8 == xcd
    int unit = idx & 31;                   // 32 blocks/graph, 16 rows each
    int rowbase = (g << 9) + (unit << 4);

    int c = tid & 63, rl = tid >> 6;
    for (int rr = 0; rr < 4; ++rr) {
        int row = rowbase + rr * 4 + rl;
        const float4* fr = (const float4*)(feats + (row << 5));
        float as = gW[(g << 6) + c];
        float at = 0.f;
        #pragma unroll
        for (int k4 = 0; k4 < 8; ++k4) {
            float4 f = fr[k4];
            int kb = k4 * 4;
            as = fmaf(f.x, Wb[(kb + 0) * HA + c], as); at = fmaf(f.x, Wc[(kb + 0) * HA + c], at);
            as = fmaf(f.y, Wb[(kb + 1) * HA + c], as); at = fmaf(f.y, Wc[(kb + 1) * HA + c], at);
            as = fmaf(f.z, Wb[(kb + 2) * HA + c], as); at = fmaf(f.z, Wc[(kb + 2) * HA + c], at);
            as = fmaf(f.w, Wb[(kb + 3) * HA + c], as); at = fmaf(f.w, Wc[(kb + 3) * HA + c], at);
        }
        pre_s[(row << 6) + c] = as;
        pre_t[(row << 6) + c] = at;
    }
}

// ---------------------------------------------------------------- pack W2 into MFMA B-fragments
__global__ void k_packW2(const float* __restrict__ W2, short* __restrict__ wfrag) {
    int lane = threadIdx.x;
    if (lane < 64) {
        #pragma unroll
        for (int f = 0; f < 8; ++f) {
            int nt = f >> 1, kh = f & 1;
            int n = nt * 16 + (lane & 15);
            int kbase = kh * 32 + (lane >> 4) * 8;
            #pragma unroll
            for (int j = 0; j < 8; ++j)
                wfrag[(f * 64 + lane) * 8 + j] = f2bf(W2[(kbase + j) * HA + n]);
        }
    }
}

// ---------------------------------------------------------------- actor: MFMA over edges
// XCD-swizzled (round 6: FETCH 131->12 MB) + software-pipelined gathers
// (round 7): all 16 edge indices loaded up front, then a 1-deep pipeline —
// while iteration it computes (cvt+MFMA+reduce), it+1's 8 L2 gathers are in
// flight. Attacks the latency-bound profile (VALUBusy 19%, MfmaUtil 5%).
__global__ __launch_bounds__(256) void k_actor(const float* __restrict__ pre_s,
                                               const float* __restrict__ pre_t,
                                               const int* __restrict__ esrc,
                                               const int* __restrict__ edst,
                                               const short* __restrict__ wfrag,
                                               const float* __restrict__ b2,
                                               const float* __restrict__ b3,
                                               const float* __restrict__ W3,
                                               float* __restrict__ logits) {
    int lane = threadIdx.x & 63;
    int wv   = threadIdx.x >> 6;
    int b    = blockIdx.x;                 // 0..2047
    int xcd  = b & 7;
    int idx  = b >> 3;                     // 0..255
    int g    = xcd + ((idx >> 5) << 3);    // graph, g%8 == xcd
    int unit = idx & 31;                   // 32 blocks per graph
    int r16  = lane & 15;
    int kg   = lane >> 4;          // k-group 0..3
    int kg2  = kg * 2;
    int tb   = (g << 10) + (unit << 5) + (wv << 3);   // tile base (8 tiles/wave)

    const bf16x8* wf = (const bf16x8*)wfrag;
    bf16x8 bw0 = wf[0 * 64 + lane];
    bf16x8 bw1 = wf[1 * 64 + lane];
    bf16x8 bw2 = wf[2 * 64 + lane];
    bf16x8 bw3 = wf[3 * 64 + lane];
    bf16x8 bw4 = wf[4 * 64 + lane];
    bf16x8 bw5 = wf[5 * 64 + lane];
    bf16x8 bw6 = wf[6 * 64 + lane];
    bf16x8 bw7 = wf[7 * 64 + lane];

    float b2c0 = b2[r16],      b2c1 = b2[16 + r16];
    float b2c2 = b2[32 + r16], b2c3 = b2[48 + r16];
    float w3c0 = W3[r16],      w3c1 = W3[16 + r16];
    float w3c2 = W3[32 + r16], w3c3 = W3[48 + r16];
    float b3v = b3[0];

    // all 16 edge indices up front (coalesced, L2-hot)
    int sa[8], ta[8];
    #pragma unroll
    for (int it = 0; it < 8; ++it) {
        int e = ((tb + it) << 4) + r16;
        sa[it] = esrc[e];
        ta[it] = edst[e];
    }

    // prime the pipeline with tile 0's gathers
    float4 cs0, cs1, cs2, cs3, ct0, ct1, ct2, ct3;
    {
        const float4* ps = (const float4*)(pre_s + (sa[0] << 6));
        const float4* pt = (const float4*)(pre_t + (ta[0] << 6));
        cs0 = ps[kg2]; cs1 = ps[kg2 + 1]; cs2 = ps[kg2 + 8]; cs3 = ps[kg2 + 9];
        ct0 = pt[kg2]; ct1 = pt[kg2 + 1]; ct2 = pt[kg2 + 8]; ct3 = pt[kg2 + 9];
    }

    #pragma unroll
    for (int it = 0; it < 8; ++it) {
        // issue next tile's gathers (clamped at the tail: redundant L1-hot reload)
        int nx = (it < 7) ? it + 1 : 7;
        const float4* ps = (const float4*)(pre_s + (sa[nx] << 6));
        const float4* pt = (const float4*)(pre_t + (ta[nx] << 6));
        float4 ns0 = ps[kg2], ns1 = ps[kg2 + 1], ns2 = ps[kg2 + 8], ns3 = ps[kg2 + 9];
        float4 nt0 = pt[kg2], nt1 = pt[kg2 + 1], nt2 = pt[kg2 + 8], nt3 = pt[kg2 + 9];

        // compute on current tile
        bf16x8 a0, a1;
        a0[0] = f2bf(fmaxf(cs0.x + ct0.x, 0.f));
        a0[1] = f2bf(fmaxf(cs0.y + ct0.y, 0.f));
        a0[2] = f2bf(fmaxf(cs0.z + ct0.z, 0.f));
        a0[3] = f2bf(fmaxf(cs0.w + ct0.w, 0.f));
        a0[4] = f2bf(fmaxf(cs1.x + ct1.x, 0.f));
        a0[5] = f2bf(fmaxf(cs1.y + ct1.y, 0.f));
        a0[6] = f2bf(fmaxf(cs1.z + ct1.z, 0.f));
        a0[7] = f2bf(fmaxf(cs1.w + ct1.w, 0.f));
        a1[0] = f2bf(fmaxf(cs2.x + ct2.x, 0.f));
        a1[1] = f2bf(fmaxf(cs2.y + ct2.y, 0.f));
        a1[2] = f2bf(fmaxf(cs2.z + ct2.z, 0.f));
        a1[3] = f2bf(fmaxf(cs2.w + ct2.w, 0.f));
        a1[4] = f2bf(fmaxf(cs3.x + ct3.x, 0.f));
        a1[5] = f2bf(fmaxf(cs3.y + ct3.y, 0.f));
        a1[6] = f2bf(fmaxf(cs3.z + ct3.z, 0.f));
        a1[7] = f2bf(fmaxf(cs3.w + ct3.w, 0.f));

        f32x4 acc0 = {0.f, 0.f, 0.f, 0.f};
        f32x4 acc1 = {0.f, 0.f, 0.f, 0.f};
        f32x4 acc2 = {0.f, 0.f, 0.f, 0.f};
        f32x4 acc3 = {0.f, 0.f, 0.f, 0.f};
        acc0 = __builtin_amdgcn_mfma_f32_16x16x32_bf16(a0, bw0, acc0, 0, 0, 0);
        acc0 = __builtin_amdgcn_mfma_f32_16x16x32_bf16(a1, bw1, acc0, 0, 0, 0);
        acc1 = __builtin_amdgcn_mfma_f32_16x16x32_bf16(a0, bw2, acc1, 0, 0, 0);
        acc1 = __builtin_amdgcn_mfma_f32_16x16x32_bf16(a1, bw3, acc1, 0, 0, 0);
        acc2 = __builtin_amdgcn_mfma_f32_16x16x32_bf16(a0, bw4, acc2, 0, 0, 0);
        acc2 = __builtin_amdgcn_mfma_f32_16x16x32_bf16(a1, bw5, acc2, 0, 0, 0);
        acc3 = __builtin_amdgcn_mfma_f32_16x16x32_bf16(a0, bw6, acc3, 0, 0, 0);
        acc3 = __builtin_amdgcn_mfma_f32_16x16x32_bf16(a1, bw7, acc3, 0, 0, 0);

        float p0 = fmaxf(acc0[0] + b2c0, 0.f) * w3c0 + fmaxf(acc1[0] + b2c1, 0.f) * w3c1
                 + fmaxf(acc2[0] + b2c2, 0.f) * w3c2 + fmaxf(acc3[0] + b2c3, 0.f) * w3c3;
        float p1 = fmaxf(acc0[1] + b2c0, 0.f) * w3c0 + fmaxf(acc1[1] + b2c1, 0.f) * w3c1
                 + fmaxf(acc2[1] + b2c2, 0.f) * w3c2 + fmaxf(acc3[1] + b2c3, 0.f) * w3c3;
        float p2 = fmaxf(acc0[2] + b2c0, 0.f) * w3c0 + fmaxf(acc1[2] + b2c1, 0.f) * w3c1
                 + fmaxf(acc2[2] + b2c2, 0.f) * w3c2 + fmaxf(acc3[2] + b2c3, 0.f) * w3c3;
        float p3 = fmaxf(acc0[3] + b2c0, 0.f) * w3c0 + fmaxf(acc1[3] + b2c1, 0.f) * w3c1
                 + fmaxf(acc2[3] + b2c2, 0.f) * w3c2 + fmaxf(acc3[3] + b2c3, 0.f) * w3c3;

        #pragma unroll
        for (int m = 1; m < 16; m <<= 1) {
            p0 += __shfl_xor(p0, m);
            p1 += __shfl_xor(p1, m);
            p2 += __shfl_xor(p2, m);
            p3 += __shfl_xor(p3, m);
        }
        if (r16 == 0) {
            float4 o;
            o.x = p0 + b3v; o.y = p1 + b3v; o.z = p2 + b3v; o.w = p3 + b3v;
            ((float4*)(logits + ((tb + it) << 4)))[kg] = o;
        }

        // rotate pipeline registers
        cs0 = ns0; cs1 = ns1; cs2 = ns2; cs3 = ns3;
        ct0 = nt0; ct1 = nt1; ct2 = nt2; ct3 = nt3;
    }
}

// ---------------------------------------------------------------- per-graph softmax
// 64 blocks: block b -> graph b; b%8 == g%8 matches the actor's logits XCD.
__global__ __launch_bounds__(256) void k_softmax(const float* __restrict__ logits,
                                                 float* __restrict__ pi) {
    int g = blockIdx.x;
    const float* lg = logits + g * EE;
    __shared__ float wred[4];
    __shared__ float bval;
    int tid = threadIdx.x;
    int wid = tid >> 6, lane = tid & 63;

    float m = -1e30f;
    for (int i = tid; i < EE; i += 256) m = fmaxf(m, lg[i]);
    #pragma unroll
    for (int off = 32; off; off >>= 1) m = fmaxf(m, __shfl_xor(m, off));
    if (lane == 0) wred[wid] = m;
    __syncthreads();
    if (tid == 0) bval = fmaxf(fmaxf(wred[0], wred[1]), fmaxf(wred[2], wred[3]));
    __syncthreads();
    float gm = bval;

    float ssum = 0.f;
    for (int i = tid; i < EE; i += 256) ssum += expf(lg[i] - gm);
    #pragma unroll
    for (int off = 32; off; off >>= 1) ssum += __shfl_xor(ssum, off);
    if (lane == 0) wred[wid] = ssum;
    __syncthreads();
    if (tid == 0) bval = wred[0] + wred[1] + wred[2] + wred[3];
    __syncthreads();
    float inv = 1.f / bval;
    for (int i = tid; i < EE; i += 256) pi[g * EE + i] = expf(lg[i] - gm) * inv;
}

// ---------------------------------------------------------------- launch
extern "C" void kernel_launch(void* const* d_in, const int* in_sizes, int n_in,
                              void* d_out, int out_size, void* d_ws, size_t ws_size,
                              hipStream_t stream) {
    const float* x      = (const float*)d_in[0];
    const int*   ei     = (const int*)d_in[1];
    const float* ginW   = (const float*)d_in[3];   // [L,M,D,D]
    const float* ginb   = (const float*)d_in[4];   // [L,M,D]
    const float* ging   = (const float*)d_in[5];   // [L,M-1,D]
    const float* ginbe  = (const float*)d_in[6];   // [L,M-1,D]
    const float* aW1 = (const float*)d_in[7];
    const float* ab1 = (const float*)d_in[8];
    const float* aW2 = (const float*)d_in[9];
    const float* ab2 = (const float*)d_in[10];
    const float* aW3 = (const float*)d_in[11];
    const float* ab3 = (const float*)d_in[12];
    const float* cW1 = (const float*)d_in[13];
    const float* cb1 = (const float*)d_in[14];
    const float* cW2 = (const float*)d_in[15];
    const float* cb2 = (const float*)d_in[16];
    const float* cW3 = (const float*)d_in[17];
    const float* cb3 = (const float*)d_in[18];

    const int* esrc = ei;
    const int* edst = ei + TOTE;

    // workspace layout (floats):
    //   w0..w3 : 4 x 1M  feature temps (pre_t aliases w0+w1, logits aliases w3)
    //   nbr    : 2M ints @ +4M   (aliased by pre_s after GIN layers)
    //   small  : @ +6M   stats/gemb/gW/wfrag/cnt/off/cursor
    float* ws     = (float*)d_ws;
    float* w0     = ws;
    float* w1     = ws + 1 * 1048576;
    float* w2     = ws + 2 * 1048576;
    float* w3     = ws + 3 * 1048576;
    int*   nbr    = (int*)(ws + 4 * 1048576);   // 2M ints
    float* pre_s  = ws + 4 * 1048576;           // alias (used after nbr dead)
    float* small  = ws + 6 * 1048576;
    float* pre_t  = w0;                         // 2M floats (w0+w1)
    float* logits = w3;

    float* stats  = small;                      // 6 x 64
    float* gemb   = small + 512;                // 64 x 32
    float* gW     = small + 2560;               // 64 x 64
    short* wfrag  = (short*)(small + 6656);     // 8 x 64 x 8 bf16
    int*   cnt    = (int*)(small + 9216);       // 32768
    int*   off    = cnt + NTOT;                 // 32769
    int*   cursor = off + NTOT + 1;             // 32768

    float* out_pi = (float*)d_out;
    float* out_v  = out_pi + TOTE;

    #define GW(l, i)  (ginW  + ((l) * 3 + (i)) * DD * DD)
    #define GB(l, i)  (ginb  + ((l) * 3 + (i)) * DD)
    #define GG(l, i)  (ging  + ((l) * 2 + (i)) * DD)
    #define GBE(l, i) (ginbe + ((l) * 2 + (i)) * DD)
    #define ST(i)     (stats + (i) * 64)

    k_zero<<<1, 384, 0, stream>>>(stats);
    k_packW2<<<1, 64, 0, stream>>>(aW2, wfrag);

    // ---- CSR build (once; edge_index is layer-invariant)
    hipMemsetAsync(cnt, 0, NTOT * sizeof(int), stream);
    k_hist<<<TOTE / 256, 256, 0, stream>>>(esrc, edst, cnt);
    k_scan<<<BB, 512, 0, stream>>>(cnt, off, cursor);
    k_scatter<<<TOTE / 256, 256, 0, stream>>>(esrc, edst, cursor, nbr);

    // ---- layer 0 (input = x)
    k_aggmm<<<NTOT / 64, 256, 0, stream>>>(x, off, nbr, GW(0, 0), GB(0, 0), w1, ST(0));
    k_bnmm<<<NTOT / 64, 256, 0, stream>>>(w1, ST(0), GG(0, 0), GBE(0, 0),
                                          GW(0, 1), GB(0, 1), w0, ST(1));
    k_bnmm<<<NTOT / 64, 256, 0, stream>>>(w0, ST(1), GG(0, 1), GBE(0, 1),
                                          GW(0, 2), GB(0, 2), w2, nullptr);

    // ---- layer 1 (feats = w2)
    k_aggmm<<<NTOT / 64, 256, 0, stream>>>(w2, off, nbr, GW(1, 0), GB(1, 0), w1, ST(2));
    k_bnmm<<<NTOT / 64, 256, 0, stream>>>(w1, ST(2), GG(1, 0), GBE(1, 0),
                                          GW(1, 1), GB(1, 1), w0, ST(3));
    k_bnmm<<<NTOT / 64, 256, 0, stream>>>(w0, ST(3), GG(1, 1), GBE(1, 1),
                                          GW(1, 2), GB(1, 2), w3, nullptr);

    // ---- layer 2 (feats = w3)
    k_aggmm<<<NTOT / 64, 256, 0, stream>>>(w3, off, nbr, GW(2, 0), GB(2, 0), w1, ST(4));
    k_bnmm<<<NTOT / 64, 256, 0, stream>>>(w1, ST(4), GG(2, 0), GBE(2, 0),
                                          GW(2, 1), GB(2, 1), w0, ST(5));
    k_bnmm<<<NTOT / 64, 256, 0, stream>>>(w0, ST(5), GG(2, 1), GBE(2, 1),
                                          GW(2, 2), GB(2, 2), w2, nullptr);
    // final feats in w2

    // ---- heads
    k_pool_critic<<<BB, 256, 0, stream>>>(w2, gemb, cW1, cb1, cW2, cb2, cW3, cb3, out_v);
    k_gembW<<<16, 256, 0, stream>>>(gemb, aW1, ab1, gW);
    k_pre<<<NTOT / 16, 256, 0, stream>>>(w2, aW1, gW, pre_s, pre_t);
    k_actor<<<2048, 256, 0, stream>>>(pre_s, pre_t, esrc, edst, wfrag,
                                      ab2, ab3, aW3, logits);
    k_softmax<<<BB, 256, 0, stream>>>(logits, out_pi);

    #undef GW
    #undef GB
    #undef GG
    #undef GBE
    #undef ST
}

// Round 13
// 512.705 us; speedup vs baseline: 4.3912x; 1.0765x over previous
//
#include <hip/hip_runtime.h>
#include <hip/hip_bf16.h>
#include <math.h>

// Problem constants (match reference)
#define BB    64          // graphs
#define NN    512         // nodes per graph
#define DD    32          // feature dim
#define EE    16384       // edges per graph
#define NTOT  32768       // B*N total nodes
#define TOTE  1048576     // B*E total edges
#define NDIR  2097152     // 2*TOTE edge-dirs
#define HA    64
#define HC    64
#define BN_EPS 1e-5f

typedef __attribute__((ext_vector_type(8))) short bf16x8;
typedef __attribute__((ext_vector_type(4))) float f32x4;

__device__ __forceinline__ short f2bf(float f) {
    union { __hip_bfloat16 h; short s; } u;
    u.h = __float2bfloat16(f);
    return u.s;
}
__device__ __forceinline__ float bf2f(short s) {
    union { unsigned int i; float f; } u;
    u.i = ((unsigned int)(unsigned short)s) << 16;
    return u.f;
}

// ---------------------------------------------------------------- prep: zero stats+cnt, pack W2
// block 0: zero stats; blocks 1..128: zero cnt; block 129: pack W2 fragments.
__global__ __launch_bounds__(256) void k_prep(float* __restrict__ stats,
                                              int* __restrict__ cnt,
                                              const float* __restrict__ W2,
                                              short* __restrict__ wfrag) {
    int b = blockIdx.x;
    if (b == 0) {
        if (threadIdx.x < 384) stats[threadIdx.x] = 0.f;
    } else if (b <= 128) {
        cnt[(b - 1) * 256 + threadIdx.x] = 0;
    } else {
        int lane = threadIdx.x;
        if (lane < 64) {
            #pragma unroll
            for (int f = 0; f < 8; ++f) {
                int nt = f >> 1, kh = f & 1;
                int n = nt * 16 + (lane & 15);
                int kbase = kh * 32 + (lane >> 4) * 8;
                #pragma unroll
                for (int j = 0; j < 8; ++j)
                    wfrag[(f * 64 + lane) * 8 + j] = f2bf(W2[(kbase + j) * HA + n]);
            }
        }
    }
}

// ================================================================ CSR build
__global__ __launch_bounds__(256) void k_hist(const int* __restrict__ esrc,
                                              const int* __restrict__ edst,
                                              int* __restrict__ cnt) {
    int e = blockIdx.x * 256 + threadIdx.x;
    int s = esrc[e];
    int t = edst[e];
    atomicAdd(&cnt[t], 1);
    atomicAdd(&cnt[s], 1);
}

__global__ __launch_bounds__(512) void k_scan(const int* __restrict__ cnt,
                                              int* __restrict__ off,
                                              int* __restrict__ cursor) {
    __shared__ int buf0[512], buf1[512];
    int g = blockIdx.x, tid = threadIdx.x;
    int me = cnt[g * 512 + tid];
    buf0[tid] = me;
    __syncthreads();
    int* s = buf0; int* d = buf1;
    for (int dd = 1; dd < 512; dd <<= 1) {
        d[tid] = s[tid] + (tid >= dd ? s[tid - dd] : 0);
        __syncthreads();
        int* tmp = s; s = d; d = tmp;
    }
    int excl = s[tid] - me;
    int val = g * 32768 + excl;
    off[g * 512 + tid] = val;
    cursor[g * 512 + tid] = val;
    if (g == 0 && tid == 0) off[NTOT] = NDIR;
}

__global__ __launch_bounds__(256) void k_scatter(const int* __restrict__ esrc,
                                                 const int* __restrict__ edst,
                                                 int* __restrict__ cursor,
                                                 int* __restrict__ nbr) {
    int e = blockIdx.x * 256 + threadIdx.x;
    int s = esrc[e];
    int t = edst[e];
    nbr[atomicAdd(&cursor[t], 1)] = s;
    nbr[atomicAdd(&cursor[s], 1)] = t;
}

// ---------------------------------------------------------------- fused agg + first linear
// XCD-swizzled: graph g pinned to XCD g%8 so feats gathers stay L2-local.
__global__ __launch_bounds__(256) void k_aggmm(const float* __restrict__ feats,
                                               const int* __restrict__ off,
                                               const int* __restrict__ nbr,
                                               const float* __restrict__ W,
                                               const float* __restrict__ bias,
                                               float* __restrict__ Hout,
                                               float* __restrict__ stats) {
    __shared__ float Ysh[64][32];    // 8 KB
    __shared__ float Wsh[DD * DD];   // 4 KB
    __shared__ float red[8][64];     // 2 KB
    int tid = threadIdx.x;
    int b = blockIdx.x;
    int xcd = b & 7, idx = b >> 3;
    int g = xcd + ((idx >> 3) << 3);
    int unit = idx & 7;
    int rowbase = (g << 9) + (unit << 6);   // 64 nodes per block

    for (int i = tid; i < DD * DD; i += 256) Wsh[i] = W[i];

    int dl = tid & 7, ng = tid >> 3;
    const float4* f4 = (const float4*)feats;
    #pragma unroll
    for (int pass = 0; pass < 2; ++pass) {
        int v = rowbase + pass * 32 + ng;
        float4 acc = f4[v * 8 + dl];         // self term
        int j = off[v], e = off[v + 1];
        for (; j + 1 < e; j += 2) {
            int u0 = nbr[j], u1 = nbr[j + 1];
            float4 a = f4[u0 * 8 + dl];
            float4 c = f4[u1 * 8 + dl];
            acc.x += a.x + c.x; acc.y += a.y + c.y;
            acc.z += a.z + c.z; acc.w += a.w + c.w;
        }
        if (j < e) {
            float4 a = f4[nbr[j] * 8 + dl];
            acc.x += a.x; acc.y += a.y; acc.z += a.z; acc.w += a.w;
        }
        *(float4*)&Ysh[pass * 32 + ng][dl * 4] = acc;
    }
    __syncthreads();

    int c = tid & 31, rg = tid >> 5;
    float bcol = bias[c];
    float bsum = 0.f, bsq = 0.f;
    for (int rr = 0; rr < 8; ++rr) {
        int r = rg * 8 + rr;
        const float4* xr = (const float4*)Ysh[r];
        float accv = bcol;
        #pragma unroll
        for (int k4 = 0; k4 < 8; ++k4) {
            float4 xv = xr[k4];
            int kb = k4 * 4;
            accv = fmaf(xv.x, Wsh[(kb + 0) * DD + c], accv);
            accv = fmaf(xv.y, Wsh[(kb + 1) * DD + c], accv);
            accv = fmaf(xv.z, Wsh[(kb + 2) * DD + c], accv);
            accv = fmaf(xv.w, Wsh[(kb + 3) * DD + c], accv);
        }
        Hout[((rowbase + r) << 5) + c] = accv;
        bsum += accv; bsq += accv * accv;
    }
    red[rg][c] = bsum;
    red[rg][32 + c] = bsq;
    __syncthreads();
    if (tid < 64) {
        float v = 0.f;
        #pragma unroll
        for (int i = 0; i < 8; ++i) v += red[i][tid];
        atomicAdd(&stats[tid], v);
    }
}

// ---------------------------------------------------------------- relu(bn(Hin)) @ W + b
__global__ __launch_bounds__(256) void k_bnmm(const float* __restrict__ Hin,
                                              const float* __restrict__ instats,
                                              const float* __restrict__ gamma,
                                              const float* __restrict__ beta,
                                              const float* __restrict__ W,
                                              const float* __restrict__ bias,
                                              float* __restrict__ Hout,
                                              float* __restrict__ outstats) {
    __shared__ float Wsh[DD * DD];
    __shared__ float As[DD], Cs[DD];
    __shared__ float red[8][64];
    int tid = threadIdx.x;
    int b = blockIdx.x;
    int xcd = b & 7, idx = b >> 3;
    int g = xcd + ((idx >> 3) << 3);
    int unit = idx & 7;
    int rowbase = (g << 9) + (unit << 6);

    for (int i = tid; i < DD * DD; i += 256) Wsh[i] = W[i];
    if (tid < DD) {
        float s  = instats[tid];
        float q  = instats[DD + tid];
        float mu = s * (1.f / NTOT);
        float var = q * (1.f / NTOT) - mu * mu;
        float a  = gamma[tid] * rsqrtf(var + BN_EPS);
        As[tid]  = a;
        Cs[tid]  = beta[tid] - mu * a;
    }
    __syncthreads();

    int c = tid & 31, rg = tid >> 5;
    float bcol = bias[c];
    float bsum = 0.f, bsq = 0.f;
    for (int rr = 0; rr < 8; ++rr) {
        int row = rowbase + rg * 8 + rr;
        const float4* xr = (const float4*)(Hin + (row << 5));
        float accv = bcol;
        #pragma unroll
        for (int k4 = 0; k4 < 8; ++k4) {
            float4 xv = xr[k4];
            int kb = k4 * 4;
            float xn;
            xn = fmaxf(fmaf(xv.x, As[kb + 0], Cs[kb + 0]), 0.f);
            accv = fmaf(xn, Wsh[(kb + 0) * DD + c], accv);
            xn = fmaxf(fmaf(xv.y, As[kb + 1], Cs[kb + 1]), 0.f);
            accv = fmaf(xn, Wsh[(kb + 1) * DD + c], accv);
            xn = fmaxf(fmaf(xv.z, As[kb + 2], Cs[kb + 2]), 0.f);
            accv = fmaf(xn, Wsh[(kb + 2) * DD + c], accv);
            xn = fmaxf(fmaf(xv.w, As[kb + 3], Cs[kb + 3]), 0.f);
            accv = fmaf(xn, Wsh[(kb + 3) * DD + c], accv);
        }
        Hout[(row << 5) + c] = accv;
        bsum += accv; bsq += accv * accv;
    }
    if (outstats) {
        red[rg][c] = bsum;
        red[rg][32 + c] = bsq;
        __syncthreads();
        if (tid < 64) {
            float v = 0.f;
            #pragma unroll
            for (int i = 0; i < 8; ++i) v += red[i][tid];
            atomicAdd(&outstats[tid], v);
        }
    }
}

// ---------------------------------------------------------------- pool + critic + gembW
// 64 blocks: block b -> graph b. Also computes gW[g][c] = ab1[c] + gemb[g]@aW1a
// (folds the old k_gembW dispatch in).
__global__ __launch_bounds__(256) void k_pool_critic(const float* __restrict__ feats,
                                                     float* __restrict__ gemb,
                                                     const float* __restrict__ W1,
                                                     const float* __restrict__ b1,
                                                     const float* __restrict__ W2,
                                                     const float* __restrict__ b2,
                                                     const float* __restrict__ W3,
                                                     const float* __restrict__ b3,
                                                     const float* __restrict__ aW1,
                                                     const float* __restrict__ ab1,
                                                     float* __restrict__ gW,
                                                     float* __restrict__ value) {
    int g = blockIdx.x;
    __shared__ float red[8][DD];
    __shared__ float ge[DD];
    __shared__ float h1[HC];
    __shared__ float h2[HC];
    int tid = threadIdx.x;
    int d = tid & 31, grp = tid >> 5;
    float s = 0.f;
    const float* fg = feats + g * NN * DD;
    for (int n = grp; n < NN; n += 8) s += fg[n * DD + d];
    red[grp][d] = s;
    __syncthreads();
    if (tid < DD) {
        float t = 0.f;
        #pragma unroll
        for (int i = 0; i < 8; ++i) t += red[i][tid];
        t *= (1.f / NN);
        ge[tid] = t;
        gemb[g * DD + tid] = t;
    }
    __syncthreads();
    // actor first-layer state part (was k_gembW)
    if (tid >= 64 && tid < 128) {
        int c = tid - 64;
        float a = ab1[c];
        #pragma unroll 4
        for (int k = 0; k < DD; ++k) a = fmaf(ge[k], aW1[k * HA + c], a);
        gW[(g << 6) + c] = a;
    }
    if (tid < HC) {
        float a = b1[tid];
        for (int k = 0; k < DD; ++k) a = fmaf(ge[k], W1[k * HC + tid], a);
        h1[tid] = fmaxf(a, 0.f);
    }
    __syncthreads();
    if (tid < HC) {
        float a = b2[tid];
        for (int k = 0; k < HC; ++k) a = fmaf(h1[k], W2[k * HC + tid], a);
        h2[tid] = fmaxf(a, 0.f);
    }
    __syncthreads();
    if (tid < 64) {
        float p = h2[tid] * W3[tid];
        #pragma unroll
        for (int off = 32; off; off >>= 1) p += __shfl_xor(p, off);
        if (tid == 0) value[g] = p + b3[0];
    }
}

// ---------------------------------------------------------------- per-node actor precompute
__global__ __launch_bounds__(256) void k_pre(const float* __restrict__ feats,
                                             const float* __restrict__ W1,
                                             const float* __restrict__ gW,
                                             float* __restrict__ pre_s,
                                             float* __restrict__ pre_t) {
    __shared__ float Wb[DD * HA];   // 8 KB
    __shared__ float Wc[DD * HA];   // 8 KB
    int tid = threadIdx.x;
    for (int i = tid; i < DD * HA; i += 256) {
        Wb[i] = W1[DD * HA + i];       // rows 32..63 of W1
        Wc[i] = W1[2 * DD * HA + i];   // rows 64..95
    }
    __syncthreads();
    int b = blockIdx.x;                    // 2048 blocks
    int xcd = b & 7, idx = b >> 3;         // idx 0..255
    int g = xcd + ((idx >> 5) << 3);       // graph, g%8 == xcd
    int unit = idx & 31;                   // 32 blocks/graph, 16 rows each
    int rowbase = (g << 9) + (unit << 4);

    int c = tid & 63, rl = tid >> 6;
    for (int rr = 0; rr < 4; ++rr) {
        int row = rowbase + rr * 4 + rl;
        const float4* fr = (const float4*)(feats + (row << 5));
        float as = gW[(g << 6) + c];
        float at = 0.f;
        #pragma unroll
        for (int k4 = 0; k4 < 8; ++k4) {
            float4 f = fr[k4];
            int kb = k4 * 4;
            as = fmaf(f.x, Wb[(kb + 0) * HA + c], as); at = fmaf(f.x, Wc[(kb + 0) * HA + c], at);
            as = fmaf(f.y, Wb[(kb + 1) * HA + c], as); at = fmaf(f.y, Wc[(kb + 1) * HA + c], at);
            as = fmaf(f.z, Wb[(kb + 2) * HA + c], as); at = fmaf(f.z, Wc[(kb + 2) * HA + c], at);
            as = fmaf(f.w, Wb[(kb + 3) * HA + c], as); at = fmaf(f.w, Wc[(kb + 3) * HA + c], at);
        }
        pre_s[(row << 6) + c] = as;
        pre_t[(row << 6) + c] = at;
    }
}

// ---------------------------------------------------------------- actor: LDS-staged MFMA
// Round 9 showed the scattered 16B L1/TA gathers are the wall (4M transactions,
// all pipes idle). Fix: stage the graph's pre_s/pre_t tables as bf16 in LDS
// (2 x 512x64 bf16 = 128 KB) with a G4 XOR swizzle (16B slot ^= row&7) so the
// per-edge ds_read_b128 gathers are ~2-way-conflict (free). 256 blocks (4 per
// graph, 1 per CU), 16 waves each; staging is fully coalesced from L2.
__global__ __launch_bounds__(1024, 4) void k_actor(const float* __restrict__ pre_s,
                                                   const float* __restrict__ pre_t,
                                                   const int* __restrict__ esrc,
                                                   const int* __restrict__ edst,
                                                   const short* __restrict__ wfrag,
                                                   const float* __restrict__ b2,
                                                   const float* __restrict__ b3,
                                                   const float* __restrict__ W3,
                                                   float* __restrict__ logits) {
    __shared__ short sS[NN * HA];   // 64 KB bf16, swizzled
    __shared__ short sT[NN * HA];   // 64 KB bf16, swizzled
    int tid  = threadIdx.x;
    int b    = blockIdx.x;                 // 0..255
    int xcd  = b & 7;
    int idx  = b >> 3;                     // 0..31
    int g    = xcd + ((idx >> 2) << 3);    // graph, g%8 == xcd
    int part = idx & 3;                    // 4 blocks/graph, 4096 edges each

    // ---- stage both tables: f32 global (coalesced) -> bf16 LDS (swizzled)
    {
        const float4* gS4 = (const float4*)(pre_s + ((g << 9) << 6));
        const float4* gT4 = (const float4*)(pre_t + ((g << 9) << 6));
        for (int i = tid; i < NN * HA / 4; i += 1024) {   // 8192 float4 per table
            int n = i >> 4, q = i & 15;
            int addr = n * 128 + ((((q >> 1) ^ (n & 7)) << 4) | ((q & 1) << 3));
            float4 vs = gS4[i];
            float4 vt = gT4[i];
            unsigned int s0 = (unsigned short)f2bf(vs.x) | ((unsigned int)(unsigned short)f2bf(vs.y) << 16);
            unsigned int s1 = (unsigned short)f2bf(vs.z) | ((unsigned int)(unsigned short)f2bf(vs.w) << 16);
            unsigned int t0 = (unsigned short)f2bf(vt.x) | ((unsigned int)(unsigned short)f2bf(vt.y) << 16);
            unsigned int t1 = (unsigned short)f2bf(vt.z) | ((unsigned int)(unsigned short)f2bf(vt.w) << 16);
            *(unsigned int*)((char*)sS + addr)     = s0;
            *(unsigned int*)((char*)sS + addr + 4) = s1;
            *(unsigned int*)((char*)sT + addr)     = t0;
            *(unsigned int*)((char*)sT + addr + 4) = t1;
        }
    }
    __syncthreads();

    int lane = tid & 63;
    int wv   = tid >> 6;           // 16 waves
    int r16  = lane & 15;
    int kg   = lane >> 4;          // k-group 0..3

    const bf16x8* wf = (const bf16x8*)wfrag;
    bf16x8 bw0 = wf[0 * 64 + lane];
    bf16x8 bw1 = wf[1 * 64 + lane];
    bf16x8 bw2 = wf[2 * 64 + lane];
    bf16x8 bw3 = wf[3 * 64 + lane];
    bf16x8 bw4 = wf[4 * 64 + lane];
    bf16x8 bw5 = wf[5 * 64 + lane];
    bf16x8 bw6 = wf[6 * 64 + lane];
    bf16x8 bw7 = wf[7 * 64 + lane];

    float b2c0 = b2[r16],      b2c1 = b2[16 + r16];
    float b2c2 = b2[32 + r16], b2c3 = b2[48 + r16];
    float w3c0 = W3[r16],      w3c1 = W3[16 + r16];
    float w3c2 = W3[32 + r16], w3c3 = W3[48 + r16];
    float b3v = b3[0];

    int ebase   = (g << 14) + (part << 12) + (wv << 8);  // 256 edges per wave
    int tilebase = (g << 10) + (part << 8) + (wv << 4);  // 16 tiles per wave

    for (int t = 0; t < 16; ++t) {
        int e  = ebase + (t << 4) + r16;
        int sl = esrc[e] & (NN - 1);   // local node id
        int tl = edst[e] & (NN - 1);

        int sb = sl * 128, xs = (sl & 7) << 4;
        int tb = tl * 128, xt = (tl & 7) << 4;
        bf16x8 psa = *(bf16x8*)((char*)sS + sb + (((kg    ) << 4) ^ xs));
        bf16x8 psb = *(bf16x8*)((char*)sS + sb + (((kg + 4) << 4) ^ xs));
        bf16x8 pta = *(bf16x8*)((char*)sT + tb + (((kg    ) << 4) ^ xt));
        bf16x8 ptb = *(bf16x8*)((char*)sT + tb + (((kg + 4) << 4) ^ xt));

        bf16x8 a0, a1;
        #pragma unroll
        for (int j = 0; j < 8; ++j) {
            a0[j] = f2bf(fmaxf(bf2f(psa[j]) + bf2f(pta[j]), 0.f));
            a1[j] = f2bf(fmaxf(bf2f(psb[j]) + bf2f(ptb[j]), 0.f));
        }

        f32x4 acc0 = {0.f, 0.f, 0.f, 0.f};
        f32x4 acc1 = {0.f, 0.f, 0.f, 0.f};
        f32x4 acc2 = {0.f, 0.f, 0.f, 0.f};
        f32x4 acc3 = {0.f, 0.f, 0.f, 0.f};
        acc0 = __builtin_amdgcn_mfma_f32_16x16x32_bf16(a0, bw0, acc0, 0, 0, 0);
        acc0 = __builtin_amdgcn_mfma_f32_16x16x32_bf16(a1, bw1, acc0, 0, 0, 0);
        acc1 = __builtin_amdgcn_mfma_f32_16x16x32_bf16(a0, bw2, acc1, 0, 0, 0);
        acc1 = __builtin_amdgcn_mfma_f32_16x16x32_bf16(a1, bw3, acc1, 0, 0, 0);
        acc2 = __builtin_amdgcn_mfma_f32_16x16x32_bf16(a0, bw4, acc2, 0, 0, 0);
        acc2 = __builtin_amdgcn_mfma_f32_16x16x32_bf16(a1, bw5, acc2, 0, 0, 0);
        acc3 = __builtin_amdgcn_mfma_f32_16x16x32_bf16(a0, bw6, acc3, 0, 0, 0);
        acc3 = __builtin_amdgcn_mfma_f32_16x16x32_bf16(a1, bw7, acc3, 0, 0, 0);

        float p0 = fmaxf(acc0[0] + b2c0, 0.f) * w3c0 + fmaxf(acc1[0] + b2c1, 0.f) * w3c1
                 + fmaxf(acc2[0] + b2c2, 0.f) * w3c2 + fmaxf(acc3[0] + b2c3, 0.f) * w3c3;
        float p1 = fmaxf(acc0[1] + b2c0, 0.f) * w3c0 + fmaxf(acc1[1] + b2c1, 0.f) * w3c1
                 + fmaxf(acc2[1] + b2c2, 0.f) * w3c2 + fmaxf(acc3[1] + b2c3, 0.f) * w3c3;
        float p2 = fmaxf(acc0[2] + b2c0, 0.f) * w3c0 + fmaxf(acc1[2] + b2c1, 0.f) * w3c1
                 + fmaxf(acc2[2] + b2c2, 0.f) * w3c2 + fmaxf(acc3[2] + b2c3, 0.f) * w3c3;
        float p3 = fmaxf(acc0[3] + b2c0, 0.f) * w3c0 + fmaxf(acc1[3] + b2c1, 0.f) * w3c1
                 + fmaxf(acc2[3] + b2c2, 0.f) * w3c2 + fmaxf(acc3[3] + b2c3, 0.f) * w3c3;

        #pragma unroll
        for (int m = 1; m < 16; m <<= 1) {
            p0 += __shfl_xor(p0, m);
            p1 += __shfl_xor(p1, m);
            p2 += __shfl_xor(p2, m);
            p3 += __shfl_xor(p3, m);
        }
        if (r16 == 0) {
            float4 o;
            o.x = p0 + b3v; o.y = p1 + b3v; o.z = p2 + b3v; o.w = p3 + b3v;
            ((float4*)(logits + ((tilebase + t) << 4)))[kg] = o;
        }
    }
}

// ---------------------------------------------------------------- per-graph softmax
__global__ __launch_bounds__(256) void k_softmax(const float* __restrict__ logits,
                                                 float* __restrict__ pi) {
    int g = blockIdx.x;
    const float* lg = logits + g * EE;
    __shared__ float wred[4];
    __shared__ float bval;
    int tid = threadIdx.x;
    int wid = tid >> 6, lane = tid & 63;

    float m = -1e30f;
    for (int i = tid; i < EE; i += 256) m = fmaxf(m, lg[i]);
    #pragma unroll
    for (int off = 32; off; off >>= 1) m = fmaxf(m, __shfl_xor(m, off));
    if (lane == 0) wred[wid] = m;
    __syncthreads();
    if (tid == 0) bval = fmaxf(fmaxf(wred[0], wred[1]), fmaxf(wred[2], wred[3]));
    __syncthreads();
    float gm = bval;

    float ssum = 0.f;
    for (int i = tid; i < EE; i += 256) ssum += expf(lg[i] - gm);
    #pragma unroll
    for (int off = 32; off; off >>= 1) ssum += __shfl_xor(ssum, off);
    if (lane == 0) wred[wid] = ssum;
    __syncthreads();
    if (tid == 0) bval = wred[0] + wred[1] + wred[2] + wred[3];
    __syncthreads();
    float inv = 1.f / bval;
    for (int i = tid; i < EE; i += 256) pi[g * EE + i] = expf(lg[i] - gm) * inv;
}

// ---------------------------------------------------------------- launch
extern "C" void kernel_launch(void* const* d_in, const int* in_sizes, int n_in,
                              void* d_out, int out_size, void* d_ws, size_t ws_size,
                              hipStream_t stream) {
    const float* x      = (const float*)d_in[0];
    const int*   ei     = (const int*)d_in[1];
    const float* ginW   = (const float*)d_in[3];   // [L,M,D,D]
    const float* ginb   = (const float*)d_in[4];   // [L,M,D]
    const float* ging   = (const float*)d_in[5];   // [L,M-1,D]
    const float* ginbe  = (const float*)d_in[6];   // [L,M-1,D]
    const float* aW1 = (const float*)d_in[7];
    const float* ab1 = (const float*)d_in[8];
    const float* aW2 = (const float*)d_in[9];
    const float* ab2 = (const float*)d_in[10];
    const float* aW3 = (const float*)d_in[11];
    const float* ab3 = (const float*)d_in[12];
    const float* cW1 = (const float*)d_in[13];
    const float* cb1 = (const float*)d_in[14];
    const float* cW2 = (const float*)d_in[15];
    const float* cb2 = (const float*)d_in[16];
    const float* cW3 = (const float*)d_in[17];
    const float* cb3 = (const float*)d_in[18];

    const int* esrc = ei;
    const int* edst = ei + TOTE;

    float* ws     = (float*)d_ws;
    float* w0     = ws;
    float* w1     = ws + 1 * 1048576;
    float* w2     = ws + 2 * 1048576;
    float* w3     = ws + 3 * 1048576;
    int*   nbr    = (int*)(ws + 4 * 1048576);   // 2M ints
    float* pre_s  = ws + 4 * 1048576;           // alias (used after nbr dead)
    float* small  = ws + 6 * 1048576;
    float* pre_t  = w0;                         // 2M floats (w0+w1)
    float* logits = w3;

    float* stats  = small;                      // 6 x 64
    float* gemb   = small + 512;                // 64 x 32
    float* gW     = small + 2560;               // 64 x 64
    short* wfrag  = (short*)(small + 6656);     // 8 x 64 x 8 bf16
    int*   cnt    = (int*)(small + 9216);       // 32768
    int*   off    = cnt + NTOT;                 // 32769
    int*   cursor = off + NTOT + 1;             // 32768

    float* out_pi = (float*)d_out;
    float* out_v  = out_pi + TOTE;

    #define GW(l, i)  (ginW  + ((l) * 3 + (i)) * DD * DD)
    #define GB(l, i)  (ginb  + ((l) * 3 + (i)) * DD)
    #define GG(l, i)  (ging  + ((l) * 2 + (i)) * DD)
    #define GBE(l, i) (ginbe + ((l) * 2 + (i)) * DD)
    #define ST(i)     (stats + (i) * 64)

    // prep: zero stats + cnt, pack W2 (one dispatch)
    k_prep<<<130, 256, 0, stream>>>(stats, cnt, aW2, wfrag);

    // ---- CSR build (once; edge_index is layer-invariant)
    k_hist<<<TOTE / 256, 256, 0, stream>>>(esrc, edst, cnt);
    k_scan<<<BB, 512, 0, stream>>>(cnt, off, cursor);
    k_scatter<<<TOTE / 256, 256, 0, stream>>>(esrc, edst, cursor, nbr);

    // ---- layer 0 (input = x)
    k_aggmm<<<NTOT / 64, 256, 0, stream>>>(x, off, nbr, GW(0, 0), GB(0, 0), w1, ST(0));
    k_bnmm<<<NTOT / 64, 256, 0, stream>>>(w1, ST(0), GG(0, 0), GBE(0, 0),
                                          GW(0, 1), GB(0, 1), w0, ST(1));
    k_bnmm<<<NTOT / 64, 256, 0, stream>>>(w0, ST(1), GG(0, 1), GBE(0, 1),
                                          GW(0, 2), GB(0, 2), w2, nullptr);

    // ---- layer 1 (feats = w2)
    k_aggmm<<<NTOT / 64, 256, 0, stream>>>(w2, off, nbr, GW(1, 0), GB(1, 0), w1, ST(2));
    k_bnmm<<<NTOT / 64, 256, 0, stream>>>(w1, ST(2), GG(1, 0), GBE(1, 0),
                                          GW(1, 1), GB(1, 1), w0, ST(3));
    k_bnmm<<<NTOT / 64, 256, 0, stream>>>(w0, ST(3), GG(1, 1), GBE(1, 1),
                                          GW(1, 2), GB(1, 2), w3, nullptr);

    // ---- layer 2 (feats = w3)
    k_aggmm<<<NTOT / 64, 256, 0, stream>>>(w3, off, nbr, GW(2, 0), GB(2, 0), w1, ST(4));
    k_bnmm<<<NTOT / 64, 256, 0, stream>>>(w1, ST(4), GG(2, 0), GBE(2, 0),
                                          GW(2, 1), GB(2, 1), w0, ST(5));
    k_bnmm<<<NTOT / 64, 256, 0, stream>>>(w0, ST(5), GG(2, 1), GBE(2, 1),
                                          GW(2, 2), GB(2, 2), w2, nullptr);
    // final feats in w2

    // ---- heads
    k_pool_critic<<<BB, 256, 0, stream>>>(w2, gemb, cW1, cb1, cW2, cb2, cW3, cb3,
                                          aW1, ab1, gW, out_v);
    k_pre<<<NTOT / 16, 256, 0, stream>>>(w2, aW1, gW, pre_s, pre_t);
    k_actor<<<256, 1024, 0, stream>>>(pre_s, pre_t, esrc, edst, wfrag,
                                      ab2, ab3, aW3, logits);
    k_softmax<<<BB, 256, 0, stream>>>(logits, out_pi);

    #undef GW
    #undef GB
    #undef GG
    #undef GBE
    #undef ST
}